// Round 10
// baseline (426.651 us; speedup 1.0000x reference)
//
#include <hip/hip_runtime.h>
#include <cmath>

// Problem constants
#define LSIG  2097153      // signal / rfft length (= NFFT/2+1)
#define MH    2097152      // NFFT/2 (complex FFT size for packed real trick)
#define NFFTC 4194304      // 2^22
#define NT    262144       // MH/8 = threads per radix-8 FFT pass
#define NT64  32768        // MH/64 = butterflies per radix-64 pass
#define O1C   1048577
#define O2C   524289
#define O3C   262145

// conv tiling: 62 o3 positions per block
#define TO3   62
#define NB3   4229         // ceil(O3C/TO3)
// LDS row strides (dwords), both == 8 mod 32 so quad offsets spread 8 banks on reads.
// Per-row rotation rot(row) = ((row>>2)&3)*8 dwords kills the write-side quad aliasing;
// on reads the row is kt*4+quad so rot = (kt&3)*8 is lane-uniform (pattern preserved).
#define S1DW2 168          // h1 row stride (reads reach 130+3+24=157)
#define S2DW2 104          // h2 row stride (reads reach 66+24=90)

// Workspace byte offsets
#define A_OFF    0
#define B_OFF    16777216
#define C_OFF    33554432
#define D_OFF    50331656
#define PM_OFF   58720268
#define FEAT_OFF 58720272
// packed bf16 weights live in the D region (free after ksmooth), 16B aligned
#define W2Q_OFF  50331664  // 64*32*8 bf16 = 32768 B
#define W3Q_OFF  50364432  // 128*64*8 bf16 = 131072 B

struct SmultTab { int hidx[40]; float inv12[40]; int fk[40]; int maxe; };

typedef short short8 __attribute__((ext_vector_type(8)));
typedef float f32x4v __attribute__((ext_vector_type(4)));

union AFrag { uint4 q; short8 s; };
union BFrag { unsigned int u[4]; short8 s; };

__device__ __forceinline__ float lrelu(float a){ return a > 0.0f ? a : 0.2f*a; }

// bf16 pack helpers (round-nearest-even)
__device__ __forceinline__ unsigned int rbf(float f) {
  unsigned int u = __float_as_uint(f);
  u += 0x7fffu + ((u >> 16) & 1u);
  return u >> 16;
}
__device__ __forceinline__ unsigned int pack_bf2(float a, float b) {
  return rbf(a) | (rbf(b) << 16);
}

__device__ __forceinline__ float2 cadd(float2 a, float2 b){ return make_float2(a.x+b.x, a.y+b.y); }
__device__ __forceinline__ float2 csub(float2 a, float2 b){ return make_float2(a.x-b.x, a.y-b.y); }
__device__ __forceinline__ float2 cmul(float2 a, float2 b){ return make_float2(a.x*b.x - a.y*b.y, a.x*b.y + a.y*b.x); }

// multiply by -i (FWD) or +i (INV)
template<bool FWD> __device__ __forceinline__ float2 jrot(float2 z){
  return FWD ? make_float2(z.y, -z.x) : make_float2(-z.y, z.x);
}

// natural-order radix-8 DFT butterfly
template<bool FWD> __device__ __forceinline__ void dft8(float2 v[8]) {
  const float cq = 0.70710678118654752440f;
  const float S  = FWD ? -1.0f : 1.0f;
  float2 e0 = cadd(v[0], v[4]), e1 = csub(v[0], v[4]);
  float2 e2 = cadd(v[2], v[6]), e3 = csub(v[2], v[6]);
  float2 E0 = cadd(e0, e2), E2 = csub(e0, e2);
  float2 jt = jrot<FWD>(e3);
  float2 E1 = cadd(e1, jt), E3 = csub(e1, jt);
  float2 o0 = cadd(v[1], v[5]), o1 = csub(v[1], v[5]);
  float2 o2 = cadd(v[3], v[7]), o3 = csub(v[3], v[7]);
  float2 O0 = cadd(o0, o2), O2 = csub(o0, o2);
  float2 jo = jrot<FWD>(o3);
  float2 O1 = cadd(o1, jo), O3 = csub(o1, jo);
  float2 T1 = make_float2(cq, S*cq), T3 = make_float2(-cq, S*cq);
  float2 w1 = cmul(T1, O1);
  float2 w2 = jrot<FWD>(O2);
  float2 w3 = cmul(T3, O3);
  v[0] = cadd(E0, O0); v[4] = csub(E0, O0);
  v[1] = cadd(E1, w1); v[5] = csub(E1, w1);
  v[2] = cadd(E2, w2); v[6] = csub(E2, w2);
  v[3] = cadd(E3, w3); v[7] = csub(E3, w3);
}

// One Stockham radix-8 pass over MH complex points (used for the Ns=64^3 tail pass).
template<bool FWD>
__global__ __launch_bounds__(256) void kfft8(const float2* __restrict__ src,
                                             float2* __restrict__ dst, int Ns) {
  int j = blockIdx.x*256 + threadIdx.x;          // j in [0, MH/8)
  int m = j & (Ns - 1);
  float frac = (float)m / (float)(Ns * 8);       // exact (power-of-two denom)
  float th = (FWD ? -6.28318530717958647692f : 6.28318530717958647692f) * frac;
  float2 v[8];
  v[0] = src[j];
#pragma unroll
  for (int r = 1; r < 8; ++r) {
    float2 a = src[j + r*NT];
    float sn, cs;
    sincosf(th * (float)r, &sn, &cs);
    v[r] = make_float2(a.x*cs - a.y*sn, a.x*sn + a.y*cs);
  }
  dft8<FWD>(v);
  int base = ((j - m) << 3) + m;                 // (j/Ns)*Ns*8 + j%Ns
#pragma unroll
  for (int r = 0; r < 8; ++r) dst[base + r*Ns] = v[r];
}

// Stockham radix-64 pass: 32 butterflies/block, 8 lanes per butterfly,
// two in-register DFT8 stages with an in-LDS 8x8 transpose between.
// FIRST=true: reads padded real signal directly (fused kpack): A[n]=z[2n]+i z[2n+1]
template<bool FWD, bool FIRST>
__global__ __launch_bounds__(256) void kfft64(const float2* __restrict__ src,
                                              float2* __restrict__ dst, int Ns,
                                              const float* __restrict__ zin) {
  __shared__ float2 ex[32*65];                   // 65 f2/butterfly (pad vs 64)
  const int t = threadIdx.x;
  const int b = t >> 3, i = t & 7;               // butterfly-in-block, r0 index
  const int j = blockIdx.x*32 + b;               // butterfly index < NT64
  const int m = j & (Ns - 1);
  const float sgn = FWD ? -6.28318530717958647692f : 6.28318530717958647692f;
  const float invden = 1.0f / (float)(64 * Ns);  // exact (power-of-two)
  float2 v[8];
#pragma unroll
  for (int r1 = 0; r1 < 8; ++r1) {
    const int r = 8*r1 + i;
    const int n = j + r * NT64;
    float2 a;
    if (FIRST) {
      if (n < 1048576)       a = ((const float2*)zin)[n];
      else if (n == 1048576) a = make_float2(zin[2097152], 0.0f);
      else                   a = make_float2(0.0f, 0.0f);
    } else {
      a = src[n];
    }
    float sn, cs;
    sincosf(sgn * ((float)(m * r) * invden), &sn, &cs);  // W^{m r}
    v[r1] = make_float2(a.x*cs - a.y*sn, a.x*sn + a.y*cs);
  }
  dft8<FWD>(v);                                   // over r1 -> v[k1]
#pragma unroll
  for (int k1 = 0; k1 < 8; ++k1) {                // intra twiddle W64^{i k1}
    float sn, cs;
    sincosf(sgn * ((float)(i*k1) * 0.015625f), &sn, &cs);
    ex[b*65 + k1*8 + i] = make_float2(v[k1].x*cs - v[k1].y*sn, v[k1].x*sn + v[k1].y*cs);
  }
  __syncthreads();
  float2 u[8];
#pragma unroll
  for (int r0 = 0; r0 < 8; ++r0) u[r0] = ex[b*65 + i*8 + r0];
  dft8<FWD>(u);                                   // over r0 -> u[k0], k = i + 8 k0
  const int base = (j - m)*64 + m;
#pragma unroll
  for (int k0 = 0; k0 < 8; ++k0) dst[base + (8*k0 + i)*Ns] = u[k0];
}

// Pack conv2/conv3 weights to bf16, taps padded 5->8 (zero) for MFMA K-layout.
__global__ __launch_bounds__(256) void kwq(const float* __restrict__ c2w,
    const float* __restrict__ c3w, unsigned short* __restrict__ w2q,
    unsigned short* __restrict__ w3q) {
  int i = blockIdx.x*256 + threadIdx.x;
  if (i < 16384) {                     // 64 ch * 32 c1 * 8 t
    int t = i & 7, c1 = (i >> 3) & 31, ch = i >> 8;
    float v = (t < 5) ? c2w[ch*160 + c1*5 + t] : 0.0f;
    w2q[i] = (unsigned short)rbf(v);
  }
  if (i < 65536) {                     // 128 ch * 64 c2 * 8 t
    int t = i & 7, c2 = (i >> 3) & 63, ch = i >> 9;
    float v = (t < 5) ? c3w[ch*320 + c2*5 + t] : 0.0f;
    w3q[i] = (unsigned short)rbf(v);
  }
}

// prog_mean reduction
__global__ __launch_bounds__(256) void kprog(
    const float* __restrict__ tw1, const float* __restrict__ tb1,
    const float* __restrict__ tw2, const float* __restrict__ tb2,
    const float* __restrict__ tw3, const float* __restrict__ tb3,
    const float* __restrict__ hp, float* __restrict__ pm) {
  __shared__ float sw1[32], sb1[32], sw2[512], sb2[16], sw3[16], shp[8], sb31[1];
  __shared__ float red[256];
  const int tid = threadIdx.x;
  if (tid < 32) { sw1[tid] = tw1[tid]; sb1[tid] = tb1[tid]; }
  for (int q = tid; q < 512; q += 256) sw2[q] = tw2[q];
  if (tid < 16) { sb2[tid] = tb2[tid]; sw3[tid] = tw3[tid*8+1]; }
  if (tid < 8) { float s = 0.f; for (int j = 0; j < 4; ++j) s += hp[tid*4+j]; shp[tid] = s; }
  if (tid == 0) sb31[0] = tb3[1];
  __syncthreads();
  const int gid = blockIdx.x*256 + tid;          // grid = 2048 blocks -> gid < 524288
  const float Lf = 2097153.0f;
  float tnv[4], sv[4];
  int ci[4];
  float acc[4][16];
#pragma unroll
  for (int e = 0; e < 4; ++e) {
    float ti = (float)(gid + e*524288);
    float tn = ti / Lf;
    tnv[e] = tn;
    sv[e] = sinf((6.28318530717958647692f * ti) / Lf);
    ci[e] = ((int)floorf(tn * 8.0f)) & 7;
#pragma unroll
    for (int kk = 0; kk < 16; ++kk) acc[e][kk] = sb2[kk];
  }
  for (int j = 0; j < 32; ++j) {
    float a = sw1[j], b = sb1[j];
    float hj[4];
#pragma unroll
    for (int e = 0; e < 4; ++e) hj[e] = fmaxf(a*tnv[e] + b, 0.0f);
#pragma unroll
    for (int kk = 0; kk < 16; ++kk) {
      float w = sw2[j*16 + kk];
#pragma unroll
      for (int e = 0; e < 4; ++e) acc[e][kk] += hj[e]*w;
    }
  }
  float lsum = 0.0f;
#pragma unroll
  for (int e = 0; e < 4; ++e) {
    float mp1 = sb31[0];
#pragma unroll
    for (int kk = 0; kk < 16; ++kk) mp1 += fmaxf(acc[e][kk], 0.0f)*sw3[kk];
    lsum += shp[ci[e]] * (1.0f + mp1*sv[e]);
  }
  if (gid == 0) {                                 // tail element i = L-1 = 2097152
    float ti = 2097152.0f;
    float tn = ti / Lf;
    float a1[16];
    for (int kk = 0; kk < 16; ++kk) a1[kk] = sb2[kk];
    for (int j = 0; j < 32; ++j) {
      float h = fmaxf(sw1[j]*tn + sb1[j], 0.0f);
      for (int kk = 0; kk < 16; ++kk) a1[kk] += h*sw2[j*16+kk];
    }
    float mp1 = sb31[0];
    for (int kk = 0; kk < 16; ++kk) mp1 += fmaxf(a1[kk], 0.0f)*sw3[kk];
    float svx = sinf((6.28318530717958647692f * ti) / Lf);
    int cix = ((int)floorf(tn * 8.0f)) & 7;
    lsum += shp[cix] * (1.0f + mp1*svx);
  }
  red[tid] = lsum;
  __syncthreads();
  for (int off = 128; off > 0; off >>= 1) {
    if (tid < off) red[tid] += red[tid+off];
    __syncthreads();
  }
  if (tid == 0) atomicAdd(pm, red[0]);
}

// rfft split + band multipliers + harmonic windows; writes modified spectrum C and |C| into D
__global__ __launch_bounds__(256) void ksplit(const float2* __restrict__ Z,
    float2* __restrict__ C, float* __restrict__ D,
    const float* __restrict__ bwp, const float* __restrict__ fwp,
    const float* __restrict__ pm_in, SmultTab tab) {
  int k = blockIdx.x*256 + threadIdx.x;
  if (k > MH) return;
  float2 zk = Z[k & (MH-1)];
  float2 zm = Z[(MH - k) & (MH-1)];
  float2 s  = make_float2(zk.x + zm.x, zk.y - zm.y);   // Z[k] + conj(Z[M-k])
  float2 dd = make_float2(zk.x - zm.x, zk.y + zm.y);   // Z[k] - conj(Z[M-k])
  float fr = (float)k / (float)NFFTC;
  float sn, cs;
  sincosf(-6.28318530717958647692f * fr, &sn, &cs);    // e^{-2pi i k/N}
  float2 t1 = make_float2(cs*dd.x - sn*dd.y, cs*dd.y + sn*dd.x);
  float2 X  = make_float2(0.5f*(s.x + t1.y), 0.5f*(s.y - t1.x)); // Xe - 0.5 i w d
  float mv = 1.0f;
  if (k <= 38050) {                                    // bands only reach 200 Hz
    const float blo[6] = {1.0f,4.0f,8.0f,13.0f,30.0f,100.0f};
    const float bhi[6] = {4.0f,8.0f,13.0f,30.0f,100.0f,200.0f};
    const float bcn[6] = {2.5f,6.0f,10.5f,21.5f,65.0f,150.0f};
    const float bhw[6] = {0.75f,1.0f,1.25f,4.25f,17.5f,25.0f};
    float f = (float)((double)k * (22050.0/4194304.0));
#pragma unroll
    for (int b = 0; b < 6; ++b) {
      if (f >= blo[b] && f <= bhi[b]) {
        float q = (f - bcn[b]) / bhw[b];
        float mask = expf(-0.5f*q*q);
        double frd = (double)k * ((double)bcn[b] / 22050.0);
        frd -= floor(frd);
        float tm = sinf(6.28318530717958647692f * (float)frd);
        mv *= (1.0f + mask * bwp[b] * (1.0f + 0.2f*tm));
      }
    }
  }
  if (k <= tab.maxe) {
    float pm1 = 1.0f + pm_in[0] * (1.0f/8388612.0f);   // 1 + sum/(L*4)
    for (int w = 0; w < 40; ++w) {
      int dlt = k - tab.hidx[w];
      if (dlt >= -15 && dlt <= 15) {
        float x = (float)dlt * 0.2f;                   // /(WIN/3)=5
        float win = expf(-0.5f*x*x);
        float enh = fwp[tab.fk[w]] * win * tab.inv12[w] * pm1;
        mv *= (1.0f + enh);
      }
    }
  }
  float2 c = make_float2(X.x*mv, X.y*mv);
  C[k] = c;
  D[k] = sqrtf(c.x*c.x + c.y*c.y);
}

__device__ __forceinline__ float2 get_xc(int k, const float2* __restrict__ C,
                                         const float* __restrict__ D) {
  float mg = D[k];
  float ms;
  if (k == 0 || k == MH) ms = mg;
  else ms = 0.7f*mg + 0.15f*D[k-1] + 0.15f*D[k+1];
  float2 c = C[k];
  if (mg > 0.0f) { float sc = ms/mg; return make_float2(c.x*sc, c.y*sc); }
  return make_float2(ms, 0.0f);                        // angle(0)=0 convention
}

// magnitude smoothing + inverse-rfft packing (with 1/M scale folded in)
__global__ __launch_bounds__(256) void ksmooth(const float2* __restrict__ C,
    const float* __restrict__ D, float2* __restrict__ A) {
  int n = blockIdx.x*256 + threadIdx.x;                // n < MH
  float2 a = get_xc(n, C, D);
  float2 b = get_xc(MH - n, C, D);
  float2 s  = make_float2(a.x + b.x, a.y - b.y);       // X + conj(Xm)
  float2 dd = make_float2(a.x - b.x, a.y + b.y);       // X - conj(Xm)
  float fr = (float)n / (float)NFFTC;
  float sn, cs;
  sincosf(6.28318530717958647692f * fr, &sn, &cs);     // e^{+2pi i n/N}
  float2 xo = make_float2(0.5f*(cs*dd.x - sn*dd.y), 0.5f*(cs*dd.y + sn*dd.x));
  const float sc = 1.0f / (float)MH;
  A[n] = make_float2((0.5f*s.x - xo.y)*sc, (0.5f*s.y + xo.x)*sc); // (Xe + i Xo)/M
}

// Fused conv1 (VALU) + conv2/conv3 (MFMA implicit GEMM, register-stationary weights).
// LDS rows carry a per-row rotation ((row>>2)&3)*8 dwords: read-side it is
// lane-uniform ((kt&3)*8), write-side it spreads the quad aliasing -> 2-way.
__global__ __launch_bounds__(256, 3) void kconv(const float* __restrict__ x,
    const unsigned short* __restrict__ w2q, const unsigned short* __restrict__ w3q,
    const float* __restrict__ c1w, const float* __restrict__ c1b,
    const float* __restrict__ c2b, const float* __restrict__ c3b,
    float* __restrict__ feat) {
  __shared__ float sb[520];                  // base tile (517 used)
  __shared__ unsigned int sh1[32*S1DW2];     // h1 bf16 pairs (rotated rows)
  __shared__ unsigned int sh2[64*S2DW2];     // h2 bf16 pairs (rotated rows)
  __shared__ float sbias2[64], sbias3[128];
  const int tid  = threadIdx.x;
  const int blk  = blockIdx.x;
  const int s3   = blk * TO3;
  const int lane = tid & 63;
  const int wv   = tid >> 6;
  const int col  = lane & 15;
  const int quad = lane >> 4;

  // ---- prefetch conv2 A-frags (wave's 2 M-tiles x 8 K-tiles) ----
  const uint4* W2 = (const uint4*)w2q;             // idx = ch*32 + c1
  const int mt2 = (wv & 1) * 2;                    // conv2 M-tile pair base
  const int ntb2 = (wv >> 1) * 4;                  // conv2 N-tile base
  uint4 wk2[2][8];
#pragma unroll
  for (int mi = 0; mi < 2; ++mi)
#pragma unroll
    for (int kt = 0; kt < 8; ++kt)
      wk2[mi][kt] = W2[((mt2+mi)*16 + col)*32 + kt*4 + quad];

  // stage base tile + biases + zero the sh2 tail window [60,92) of every row
  {
    const int pb = 8*s3 - 14;
    for (int idx = tid; idx < 520; idx += 256) {
      int p = pb + idx;
      sb[idx] = (idx < 517 && p >= 0 && p < LSIG) ? x[p] : 0.0f;
    }
    if (tid < 64) sbias2[tid] = c2b[tid];
    else if (tid < 192) sbias3[tid-64] = c3b[tid-64];
    for (int q = tid; q < 2048; q += 256)
      sh2[(q >> 5)*S2DW2 + 60 + (q & 31)] = 0u;
  }
  __syncthreads();

  // conv1: 32 ch, positions 0..256 -> bf16 pairs at rotated rows (j in [0,134))
  {
    const int c1 = tid & 31, g = tid >> 5;
    const int rot1 = ((c1 >> 2) & 3) << 3;
    const float u0=c1w[c1*5+0], u1=c1w[c1*5+1], u2=c1w[c1*5+2], u3=c1w[c1*5+3], u4=c1w[c1*5+4];
    const float bb = c1b[c1];
    const int a1 = 4*s3 - 6;
    for (int j = g; j < 134; j += 8) {
      float r0 = 0.f, r1 = 0.f;
      if (j <= 128) {
        float v0=sb[4*j+0],v1=sb[4*j+1],v2=sb[4*j+2],v3=sb[4*j+3],v4=sb[4*j+4],v5=sb[4*j+5],v6=sb[4*j+6];
        int o0 = a1 + 2*j;
        if (o0 >= 0 && o0 < O1C)
          r0 = lrelu(bb + u0*v0+u1*v1+u2*v2+u3*v3+u4*v4);
        if (2*j+1 <= 256 && o0+1 >= 0 && o0+1 < O1C)
          r1 = lrelu(bb + u0*v2+u1*v3+u2*v4+u3*v5+u4*v6);
      }
      sh1[c1*S1DW2 + rot1 + j] = pack_bf2(r0, r1);
    }
  }
  __syncthreads();

  // conv2 MFMA: 2 mt x 4 nt, K-tiles 0..7; B-frag shared across the 2 mt
  f32x4v acc2[2][4];
#pragma unroll
  for (int mi = 0; mi < 2; ++mi)
#pragma unroll
    for (int nt = 0; nt < 4; ++nt) acc2[mi][nt] = (f32x4v){0,0,0,0};
#pragma unroll
  for (int kt = 0; kt < 8; ++kt) {
    const int c1 = kt*4 + quad;
    const int rrot = (kt & 3) << 3;                // == ((c1>>2)&3)*8, lane-uniform
#pragma unroll
    for (int nt = 0; nt < 4; ++nt) {
      const int n = (ntb2 + nt)*16 + col;
      const int base = c1*S1DW2 + rrot + n;
      BFrag bf;
      bf.u[0] = sh1[base+0]; bf.u[1] = sh1[base+1];
      bf.u[2] = sh1[base+2]; bf.u[3] = sh1[base+3];
      AFrag a0, a1; a0.q = wk2[0][kt]; a1.q = wk2[1][kt];
      acc2[0][nt] = __builtin_amdgcn_mfma_f32_16x16x32_bf16(a0.s, bf.s, acc2[0][nt], 0, 0, 0);
      acc2[1][nt] = __builtin_amdgcn_mfma_f32_16x16x32_bf16(a1.s, bf.s, acc2[1][nt], 0, 0, 0);
    }
  }

  // ---- prefetch conv3 A-frags (overlaps conv2 epilogue + barrier) ----
  const uint4* W3 = (const uint4*)w3q;             // idx = ch*64 + c2
  uint4 wk3[2][16];
#pragma unroll
  for (int mi = 0; mi < 2; ++mi)
#pragma unroll
    for (int kt = 0; kt < 16; ++kt)
      wk3[mi][kt] = W3[((2*wv+mi)*16 + col)*64 + kt*4 + quad];

  // conv2 epilogue: bias + lrelu + bounds -> h2 bf16 at rotated rows
  {
    const int a2 = 2*s3 - 2;
    unsigned short* sh2s = (unsigned short*)sh2;
    const int wrot = quad << 3;                    // ((ch>>2)&3)*8 == quad*8
#pragma unroll
    for (int nt = 0; nt < 4; ++nt) {
      const int p = (ntb2 + nt)*16 + col;
      const int o2 = a2 + p;
      const bool ok = (p < 127) && (o2 >= 0) && (o2 < O2C);
#pragma unroll
      for (int mi = 0; mi < 2; ++mi)
#pragma unroll
        for (int r = 0; r < 4; ++r) {
          const int ch = (mt2+mi)*16 + quad*4 + r;
          float v = ok ? lrelu(acc2[mi][nt][r] + sbias2[ch]) : 0.0f;
          sh2s[ch*(2*S2DW2) + 2*wrot + p] = (unsigned short)rbf(v);
        }
    }
  }
  __syncthreads();

  // conv3 MFMA: 2 mt x 4 nt, K-tiles 0..15
  {
    const int slot = (blk & 255) * 128;
    f32x4v acc3[2][4];
#pragma unroll
    for (int mi = 0; mi < 2; ++mi)
#pragma unroll
      for (int nt = 0; nt < 4; ++nt) acc3[mi][nt] = (f32x4v){0,0,0,0};
#pragma unroll
    for (int kt = 0; kt < 16; ++kt) {
      const int c2 = kt*4 + quad;
      const int rrot = (kt & 3) << 3;              // == ((c2>>2)&3)*8, lane-uniform
#pragma unroll
      for (int nt = 0; nt < 4; ++nt) {
        const int n = nt*16 + col;
        const int base = c2*S2DW2 + rrot + n;
        BFrag bf;
        bf.u[0] = sh2[base+0]; bf.u[1] = sh2[base+1];
        bf.u[2] = sh2[base+2]; bf.u[3] = sh2[base+3];
        AFrag a0, a1; a0.q = wk3[0][kt]; a1.q = wk3[1][kt];
        acc3[0][nt] = __builtin_amdgcn_mfma_f32_16x16x32_bf16(a0.s, bf.s, acc3[0][nt], 0, 0, 0);
        acc3[1][nt] = __builtin_amdgcn_mfma_f32_16x16x32_bf16(a1.s, bf.s, acc3[1][nt], 0, 0, 0);
      }
    }
    // epilogue: bias+lrelu, mask, sum over nt + col lanes, atomic to feat
#pragma unroll
    for (int mi = 0; mi < 2; ++mi)
#pragma unroll
      for (int r = 0; r < 4; ++r) {
        const int ch = (2*wv+mi)*16 + quad*4 + r;
        const float bb = sbias3[ch];
        float v = 0.0f;
#pragma unroll
        for (int nt = 0; nt < 4; ++nt) {
          const int n = nt*16 + col;
          const bool ok = (n < TO3) && (s3 + n < O3C);
          if (ok) v += lrelu(acc3[mi][nt][r] + bb);
        }
        v += __shfl_xor(v, 1);
        v += __shfl_xor(v, 2);
        v += __shfl_xor(v, 4);
        v += __shfl_xor(v, 8);
        if (col == 0) atomicAdd(&feat[slot + ch], v);
      }
  }
}

// final mean + 2-layer MLP -> one f32 scalar
__global__ __launch_bounds__(256) void kfinal(const float* __restrict__ feat,
    const float* __restrict__ mw1, const float* __restrict__ mb1,
    const float* __restrict__ mw2, const float* __restrict__ mb2,
    float* __restrict__ out) {
  __shared__ float sfeat[128];
  __shared__ float red[256];
  const int tid = threadIdx.x;
  if (tid < 128) {
    float s = 0.0f;
    for (int sl = 0; sl < 256; ++sl) s += feat[sl*128 + tid];
    sfeat[tid] = s / 262145.0f;
  }
  __syncthreads();
  float y = mb1[tid];
  for (int i = 0; i < 128; ++i) y += sfeat[i] * mw1[i*256 + tid];
  y = y > 0.0f ? y : 0.2f*y;
  red[tid] = y * mw2[tid];
  __syncthreads();
  for (int off = 128; off > 0; off >>= 1) {
    if (tid < off) red[tid] += red[tid+off];
    __syncthreads();
  }
  if (tid == 0) out[0] = red[0] + mb2[0];
}

extern "C" void kernel_launch(void* const* d_in, const int* in_sizes, int n_in,
                              void* d_out, int out_size, void* d_ws, size_t ws_size,
                              hipStream_t stream) {
  (void)in_sizes; (void)n_in; (void)out_size; (void)ws_size;
  const float* z   = (const float*)d_in[0];
  const float* bw  = (const float*)d_in[2];
  const float* fw  = (const float*)d_in[3];
  const float* hp  = (const float*)d_in[4];
  const float* tw1 = (const float*)d_in[5];
  const float* tb1 = (const float*)d_in[6];
  const float* tw2 = (const float*)d_in[7];
  const float* tb2 = (const float*)d_in[8];
  const float* tw3 = (const float*)d_in[9];
  const float* tb3 = (const float*)d_in[10];
  const float* c1w = (const float*)d_in[11];
  const float* c1b = (const float*)d_in[12];
  const float* c2w = (const float*)d_in[13];
  const float* c2b = (const float*)d_in[14];
  const float* c3w = (const float*)d_in[15];
  const float* c3b = (const float*)d_in[16];
  const float* mw1 = (const float*)d_in[17];
  const float* mb1 = (const float*)d_in[18];
  const float* mw2 = (const float*)d_in[19];
  const float* mb2 = (const float*)d_in[20];

  char* wsb = (char*)d_ws;
  float2* A    = (float2*)(wsb + A_OFF);
  float2* B    = (float2*)(wsb + B_OFF);
  float2* C    = (float2*)(wsb + C_OFF);
  float*  D    = (float*)(wsb + D_OFF);
  float*  PM   = (float*)(wsb + PM_OFF);
  float*  FEAT = (float*)(wsb + FEAT_OFF);
  unsigned short* W2Q = (unsigned short*)(wsb + W2Q_OFF);
  unsigned short* W3Q = (unsigned short*)(wsb + W3Q_OFF);

  // static harmonic-window table
  SmultTab tab;
  {
    const double spec[8] = {7.83, 528.0, 396.0, 2.5, 14.1, 432.0, 6.0, 30.0};
    int n = 0, maxe = 0;
    for (int kk = 0; kk < 8; ++kk)
      for (int m = 1; m <= 5; ++m) {
        double hf = spec[kk] * (double)m;
        if (hf >= 11025.0) continue;
        int hidx = (int)std::floor(hf * (4194304.0/22050.0) + 0.5);
        tab.hidx[n]  = hidx;
        tab.inv12[n] = (float)(1.0/std::pow((double)m, 1.2));
        tab.fk[n]    = kk;
        if (hidx + 15 > maxe) maxe = hidx + 15;
        ++n;
      }
    tab.maxe = maxe;  // n == 40
  }

  (void)hipMemsetAsync(wsb + PM_OFF, 0, 4 + 131072, stream);   // PM + FEAT accumulators
  kprog<<<2048,256,0,stream>>>(tw1,tb1,tw2,tb2,tw3,tb3,hp,PM);

  // forward cfft: radix 64,64,64,8 (kpack fused into the first pass)
  kfft64<true,true ><<<1024,256,0,stream>>>(A, A, 1,     z);
  kfft64<true,false><<<1024,256,0,stream>>>(A, B, 64,    z);
  kfft64<true,false><<<1024,256,0,stream>>>(B, A, 4096,  z);
  kfft8 <true>      <<<1024,256,0,stream>>>(A, B, 262144);

  ksplit<<<8193,256,0,stream>>>(B, C, D, bw, fw, PM, tab);
  ksmooth<<<8192,256,0,stream>>>(C, D, A);
  // D region is now free: pack MFMA weights into it
  kwq<<<256,256,0,stream>>>(c2w, c3w, W2Q, W3Q);

  // inverse cfft: radix 64,64,64,8
  kfft64<false,false><<<1024,256,0,stream>>>(A, B, 1,     z);
  kfft64<false,false><<<1024,256,0,stream>>>(B, A, 64,    z);
  kfft64<false,false><<<1024,256,0,stream>>>(A, B, 4096,  z);
  kfft8 <false>      <<<1024,256,0,stream>>>(B, A, 262144);

  kconv<<<NB3,256,0,stream>>>((const float*)A, W2Q, W3Q, c1w, c1b, c2b, c3b, FEAT);
  kfinal<<<1,256,0,stream>>>(FEAT, mw1, mb1, mw2, mb2, (float*)d_out);
}

// Round 11
// 399.364 us; speedup vs baseline: 1.0683x; 1.0683x over previous
//
#include <hip/hip_runtime.h>
#include <cmath>

// Problem constants
#define LSIG  2097153      // signal / rfft length (= NFFT/2+1)
#define MH    2097152      // NFFT/2 (complex FFT size for packed real trick)
#define NFFTC 4194304      // 2^22
#define NT    262144       // MH/8 = threads per radix-8 FFT pass
#define NT64  32768        // MH/64 = butterflies per radix-64 pass
#define O1C   1048577
#define O2C   524289
#define O3C   262145

// conv tiling: 62 o3 positions per block
#define TO3   62
#define NB3   4229         // ceil(O3C/TO3)
#define S1DW2 136          // h1 dword stride (== 8 mod 32)
#define S2DW2 72           // h2 dword stride (== 8 mod 32)

// Workspace byte offsets
#define A_OFF    0
#define B_OFF    16777216
#define C_OFF    33554432
#define D_OFF    50331656
#define PM_OFF   58720268
#define FEAT_OFF 58720272
// packed bf16 weights live in the D region (free after ksmooth), 16B aligned
#define W2Q_OFF  50331664  // 64*32*8 bf16 = 32768 B
#define W3Q_OFF  50364432  // 128*64*8 bf16 = 131072 B

struct SmultTab { int hidx[40]; float inv12[40]; int fk[40]; int maxe; };

typedef short short8 __attribute__((ext_vector_type(8)));
typedef float f32x4v __attribute__((ext_vector_type(4)));

union AFrag { uint4 q; short8 s; };
union BFrag { unsigned int u[4]; short8 s; };

__device__ __forceinline__ float lrelu(float a){ return a > 0.0f ? a : 0.2f*a; }

// HW transcendentals: v_sin_f32 / v_cos_f32 take input in REVOLUTIONS.
// All our FFT/spectral angles are exact binary fractions in [0,1) -> direct feed.
__device__ __forceinline__ float hsin(float rev){ return __builtin_amdgcn_sinf(rev); }
__device__ __forceinline__ float hcos(float rev){ return __builtin_amdgcn_cosf(rev); }

// bf16 pack helpers (round-nearest-even)
__device__ __forceinline__ unsigned int rbf(float f) {
  unsigned int u = __float_as_uint(f);
  u += 0x7fffu + ((u >> 16) & 1u);
  return u >> 16;
}
__device__ __forceinline__ unsigned int pack_bf2(float a, float b) {
  return rbf(a) | (rbf(b) << 16);
}

__device__ __forceinline__ float2 cadd(float2 a, float2 b){ return make_float2(a.x+b.x, a.y+b.y); }
__device__ __forceinline__ float2 csub(float2 a, float2 b){ return make_float2(a.x-b.x, a.y-b.y); }
__device__ __forceinline__ float2 cmul(float2 a, float2 b){ return make_float2(a.x*b.x - a.y*b.y, a.x*b.y + a.y*b.x); }

// multiply by -i (FWD) or +i (INV)
template<bool FWD> __device__ __forceinline__ float2 jrot(float2 z){
  return FWD ? make_float2(z.y, -z.x) : make_float2(-z.y, z.x);
}

// natural-order radix-8 DFT butterfly
template<bool FWD> __device__ __forceinline__ void dft8(float2 v[8]) {
  const float cq = 0.70710678118654752440f;
  const float S  = FWD ? -1.0f : 1.0f;
  float2 e0 = cadd(v[0], v[4]), e1 = csub(v[0], v[4]);
  float2 e2 = cadd(v[2], v[6]), e3 = csub(v[2], v[6]);
  float2 E0 = cadd(e0, e2), E2 = csub(e0, e2);
  float2 jt = jrot<FWD>(e3);
  float2 E1 = cadd(e1, jt), E3 = csub(e1, jt);
  float2 o0 = cadd(v[1], v[5]), o1 = csub(v[1], v[5]);
  float2 o2 = cadd(v[3], v[7]), o3 = csub(v[3], v[7]);
  float2 O0 = cadd(o0, o2), O2 = csub(o0, o2);
  float2 jo = jrot<FWD>(o3);
  float2 O1 = cadd(o1, jo), O3 = csub(o1, jo);
  float2 T1 = make_float2(cq, S*cq), T3 = make_float2(-cq, S*cq);
  float2 w1 = cmul(T1, O1);
  float2 w2 = jrot<FWD>(O2);
  float2 w3 = cmul(T3, O3);
  v[0] = cadd(E0, O0); v[4] = csub(E0, O0);
  v[1] = cadd(E1, w1); v[5] = csub(E1, w1);
  v[2] = cadd(E2, w2); v[6] = csub(E2, w2);
  v[3] = cadd(E3, w3); v[7] = csub(E3, w3);
}

// One Stockham radix-8 pass over MH complex points (used for the Ns=64^3 tail pass).
template<bool FWD>
__global__ __launch_bounds__(256) void kfft8(const float2* __restrict__ src,
                                             float2* __restrict__ dst, int Ns) {
  int j = blockIdx.x*256 + threadIdx.x;          // j in [0, MH/8)
  int m = j & (Ns - 1);
  const float ssg = FWD ? -1.0f : 1.0f;
  float frac = (float)m / (float)(Ns * 8);       // revolutions, exact
  float2 v[8];
  v[0] = src[j];
#pragma unroll
  for (int r = 1; r < 8; ++r) {
    float2 a = src[j + r*NT];
    float rev = frac * (float)r;                 // exact (<= 21 mantissa bits)
    float sn = ssg * hsin(rev), cs = hcos(rev);
    v[r] = make_float2(a.x*cs - a.y*sn, a.x*sn + a.y*cs);
  }
  dft8<FWD>(v);
  int base = ((j - m) << 3) + m;                 // (j/Ns)*Ns*8 + j%Ns
#pragma unroll
  for (int r = 0; r < 8; ++r) dst[base + r*Ns] = v[r];
}

// Stockham radix-64 pass: 32 butterflies/block, 8 lanes per butterfly,
// two in-register DFT8 stages with an in-LDS 8x8 transpose between.
// FIRST=true: reads padded real signal directly (fused kpack): A[n]=z[2n]+i z[2n+1]
template<bool FWD, bool FIRST>
__global__ __launch_bounds__(256) void kfft64(const float2* __restrict__ src,
                                              float2* __restrict__ dst, int Ns,
                                              const float* __restrict__ zin) {
  __shared__ float2 ex[32*65];                   // 65 f2/butterfly (pad vs 64)
  const int t = threadIdx.x;
  const int b = t >> 3, i = t & 7;               // butterfly-in-block, r0 index
  const int j = blockIdx.x*32 + b;               // butterfly index < NT64
  const int m = j & (Ns - 1);
  const float ssg = FWD ? -1.0f : 1.0f;
  const float invden = 1.0f / (float)(64 * Ns);  // exact (power-of-two)
  float2 v[8];
#pragma unroll
  for (int r1 = 0; r1 < 8; ++r1) {
    const int r = 8*r1 + i;
    const int n = j + r * NT64;
    float2 a;
    if (FIRST) {
      if (n < 1048576)       a = ((const float2*)zin)[n];
      else if (n == 1048576) a = make_float2(zin[2097152], 0.0f);
      else                   a = make_float2(0.0f, 0.0f);
    } else {
      a = src[n];
    }
    float rev = (float)(m * r) * invden;         // revolutions, exact (m*r < 2^24)
    float sn = ssg * hsin(rev), cs = hcos(rev);
    v[r1] = make_float2(a.x*cs - a.y*sn, a.x*sn + a.y*cs);
  }
  dft8<FWD>(v);                                   // over r1 -> v[k1]
#pragma unroll
  for (int k1 = 0; k1 < 8; ++k1) {                // intra twiddle W64^{i k1}
    float rev = (float)(i*k1) * 0.015625f;        // revolutions, exact
    float sn = ssg * hsin(rev), cs = hcos(rev);
    ex[b*65 + k1*8 + i] = make_float2(v[k1].x*cs - v[k1].y*sn, v[k1].x*sn + v[k1].y*cs);
  }
  __syncthreads();
  float2 u[8];
#pragma unroll
  for (int r0 = 0; r0 < 8; ++r0) u[r0] = ex[b*65 + i*8 + r0];
  dft8<FWD>(u);                                   // over r0 -> u[k0], k = i + 8 k0
  const int base = (j - m)*64 + m;
#pragma unroll
  for (int k0 = 0; k0 < 8; ++k0) dst[base + (8*k0 + i)*Ns] = u[k0];
}

// Pack conv2/conv3 weights to bf16, taps padded 5->8 (zero) for MFMA K-layout.
__global__ __launch_bounds__(256) void kwq(const float* __restrict__ c2w,
    const float* __restrict__ c3w, unsigned short* __restrict__ w2q,
    unsigned short* __restrict__ w3q) {
  int i = blockIdx.x*256 + threadIdx.x;
  if (i < 16384) {                     // 64 ch * 32 c1 * 8 t
    int t = i & 7, c1 = (i >> 3) & 31, ch = i >> 8;
    float v = (t < 5) ? c2w[ch*160 + c1*5 + t] : 0.0f;
    w2q[i] = (unsigned short)rbf(v);
  }
  if (i < 65536) {                     // 128 ch * 64 c2 * 8 t
    int t = i & 7, c2 = (i >> 3) & 63, ch = i >> 9;
    float v = (t < 5) ? c3w[ch*320 + c2*5 + t] : 0.0f;
    w3q[i] = (unsigned short)rbf(v);
  }
}

// prog_mean reduction
__global__ __launch_bounds__(256) void kprog(
    const float* __restrict__ tw1, const float* __restrict__ tb1,
    const float* __restrict__ tw2, const float* __restrict__ tb2,
    const float* __restrict__ tw3, const float* __restrict__ tb3,
    const float* __restrict__ hp, float* __restrict__ pm) {
  __shared__ float sw1[32], sb1[32], sw2[512], sb2[16], sw3[16], shp[8], sb31[1];
  __shared__ float red[256];
  const int tid = threadIdx.x;
  if (tid < 32) { sw1[tid] = tw1[tid]; sb1[tid] = tb1[tid]; }
  for (int q = tid; q < 512; q += 256) sw2[q] = tw2[q];
  if (tid < 16) { sb2[tid] = tb2[tid]; sw3[tid] = tw3[tid*8+1]; }
  if (tid < 8) { float s = 0.f; for (int j = 0; j < 4; ++j) s += hp[tid*4+j]; shp[tid] = s; }
  if (tid == 0) sb31[0] = tb3[1];
  __syncthreads();
  const int gid = blockIdx.x*256 + tid;          // grid = 2048 blocks -> gid < 524288
  const float Lf = 2097153.0f;
  float tnv[4], sv[4];
  int ci[4];
  float acc[4][16];
#pragma unroll
  for (int e = 0; e < 4; ++e) {
    float ti = (float)(gid + e*524288);
    float tn = ti / Lf;
    tnv[e] = tn;
    sv[e] = hsin(tn);                            // sin(2*pi*ti/L)
    ci[e] = ((int)floorf(tn * 8.0f)) & 7;
#pragma unroll
    for (int kk = 0; kk < 16; ++kk) acc[e][kk] = sb2[kk];
  }
  for (int j = 0; j < 32; ++j) {
    float a = sw1[j], b = sb1[j];
    float hj[4];
#pragma unroll
    for (int e = 0; e < 4; ++e) hj[e] = fmaxf(a*tnv[e] + b, 0.0f);
#pragma unroll
    for (int kk = 0; kk < 16; ++kk) {
      float w = sw2[j*16 + kk];
#pragma unroll
      for (int e = 0; e < 4; ++e) acc[e][kk] += hj[e]*w;
    }
  }
  float lsum = 0.0f;
#pragma unroll
  for (int e = 0; e < 4; ++e) {
    float mp1 = sb31[0];
#pragma unroll
    for (int kk = 0; kk < 16; ++kk) mp1 += fmaxf(acc[e][kk], 0.0f)*sw3[kk];
    lsum += shp[ci[e]] * (1.0f + mp1*sv[e]);
  }
  if (gid == 0) {                                 // tail element i = L-1 = 2097152
    float ti = 2097152.0f;
    float tn = ti / Lf;
    float a1[16];
    for (int kk = 0; kk < 16; ++kk) a1[kk] = sb2[kk];
    for (int j = 0; j < 32; ++j) {
      float h = fmaxf(sw1[j]*tn + sb1[j], 0.0f);
      for (int kk = 0; kk < 16; ++kk) a1[kk] += h*sw2[j*16+kk];
    }
    float mp1 = sb31[0];
    for (int kk = 0; kk < 16; ++kk) mp1 += fmaxf(a1[kk], 0.0f)*sw3[kk];
    float svx = hsin(tn);
    int cix = ((int)floorf(tn * 8.0f)) & 7;
    lsum += shp[cix] * (1.0f + mp1*svx);
  }
  red[tid] = lsum;
  __syncthreads();
  for (int off = 128; off > 0; off >>= 1) {
    if (tid < off) red[tid] += red[tid+off];
    __syncthreads();
  }
  if (tid == 0) atomicAdd(pm, red[0]);
}

// rfft split + band multipliers + harmonic windows; writes modified spectrum C and |C| into D
__global__ __launch_bounds__(256) void ksplit(const float2* __restrict__ Z,
    float2* __restrict__ C, float* __restrict__ D,
    const float* __restrict__ bwp, const float* __restrict__ fwp,
    const float* __restrict__ pm_in, SmultTab tab) {
  int k = blockIdx.x*256 + threadIdx.x;
  if (k > MH) return;
  float2 zk = Z[k & (MH-1)];
  float2 zm = Z[(MH - k) & (MH-1)];
  float2 s  = make_float2(zk.x + zm.x, zk.y - zm.y);   // Z[k] + conj(Z[M-k])
  float2 dd = make_float2(zk.x - zm.x, zk.y + zm.y);   // Z[k] - conj(Z[M-k])
  float fr = (float)k * (1.0f / (float)NFFTC);         // revolutions, exact
  float sn = -hsin(fr), cs = hcos(fr);                 // e^{-2pi i k/N}
  float2 t1 = make_float2(cs*dd.x - sn*dd.y, cs*dd.y + sn*dd.x);
  float2 X  = make_float2(0.5f*(s.x + t1.y), 0.5f*(s.y - t1.x)); // Xe - 0.5 i w d
  float mv = 1.0f;
  if (k <= 38050) {                                    // bands only reach 200 Hz
    const float blo[6] = {1.0f,4.0f,8.0f,13.0f,30.0f,100.0f};
    const float bhi[6] = {4.0f,8.0f,13.0f,30.0f,100.0f,200.0f};
    const float bcn[6] = {2.5f,6.0f,10.5f,21.5f,65.0f,150.0f};
    const float bhw[6] = {0.75f,1.0f,1.25f,4.25f,17.5f,25.0f};
    float f = (float)((double)k * (22050.0/4194304.0));
#pragma unroll
    for (int b = 0; b < 6; ++b) {
      if (f >= blo[b] && f <= bhi[b]) {
        float q = (f - bcn[b]) / bhw[b];
        float mask = expf(-0.5f*q*q);
        double frd = (double)k * ((double)bcn[b] / 22050.0);
        frd -= floor(frd);
        float tm = hsin((float)frd);                   // sin(2*pi*frd)
        mv *= (1.0f + mask * bwp[b] * (1.0f + 0.2f*tm));
      }
    }
  }
  if (k <= tab.maxe) {
    float pm1 = 1.0f + pm_in[0] * (1.0f/8388612.0f);   // 1 + sum/(L*4)
    for (int w = 0; w < 40; ++w) {
      int dlt = k - tab.hidx[w];
      if (dlt >= -15 && dlt <= 15) {
        float x = (float)dlt * 0.2f;                   // /(WIN/3)=5
        float win = expf(-0.5f*x*x);
        float enh = fwp[tab.fk[w]] * win * tab.inv12[w] * pm1;
        mv *= (1.0f + enh);
      }
    }
  }
  float2 c = make_float2(X.x*mv, X.y*mv);
  C[k] = c;
  D[k] = sqrtf(c.x*c.x + c.y*c.y);
}

__device__ __forceinline__ float2 get_xc(int k, const float2* __restrict__ C,
                                         const float* __restrict__ D) {
  float mg = D[k];
  float ms;
  if (k == 0 || k == MH) ms = mg;
  else ms = 0.7f*mg + 0.15f*D[k-1] + 0.15f*D[k+1];
  float2 c = C[k];
  if (mg > 0.0f) { float sc = ms/mg; return make_float2(c.x*sc, c.y*sc); }
  return make_float2(ms, 0.0f);                        // angle(0)=0 convention
}

// magnitude smoothing + inverse-rfft packing (with 1/M scale folded in)
__global__ __launch_bounds__(256) void ksmooth(const float2* __restrict__ C,
    const float* __restrict__ D, float2* __restrict__ A) {
  int n = blockIdx.x*256 + threadIdx.x;                // n < MH
  float2 a = get_xc(n, C, D);
  float2 b = get_xc(MH - n, C, D);
  float2 s  = make_float2(a.x + b.x, a.y - b.y);       // X + conj(Xm)
  float2 dd = make_float2(a.x - b.x, a.y + b.y);       // X - conj(Xm)
  float fr = (float)n * (1.0f / (float)NFFTC);         // revolutions, exact
  float sn = hsin(fr), cs = hcos(fr);                  // e^{+2pi i n/N}
  float2 xo = make_float2(0.5f*(cs*dd.x - sn*dd.y), 0.5f*(cs*dd.y + sn*dd.x));
  const float sc = 1.0f / (float)MH;
  A[n] = make_float2((0.5f*s.x - xo.y)*sc, (0.5f*s.y + xo.x)*sc); // (Xe + i Xo)/M
}

// Fused conv1 (VALU) + conv2/conv3 (MFMA implicit GEMM, register-stationary weights).
// (round-9 version: swizzle experiment reverted — conflicts are intrinsic b128 cost,
//  and launch_bounds(256,3) caused VGPR spills)
__global__ __launch_bounds__(256, 2) void kconv(const float* __restrict__ x,
    const unsigned short* __restrict__ w2q, const unsigned short* __restrict__ w3q,
    const float* __restrict__ c1w, const float* __restrict__ c1b,
    const float* __restrict__ c2b, const float* __restrict__ c3b,
    float* __restrict__ feat) {
  __shared__ float sb[520];                  // base tile (517 used)
  __shared__ unsigned int sh1[32*S1DW2];     // h1 bf16 pairs
  __shared__ unsigned int sh2[64*S2DW2];     // h2 bf16 pairs
  __shared__ float sbias2[64], sbias3[128];
  const int tid  = threadIdx.x;
  const int blk  = blockIdx.x;
  const int s3   = blk * TO3;
  const int lane = tid & 63;
  const int wv   = tid >> 6;
  const int col  = lane & 15;
  const int quad = lane >> 4;

  // ---- prefetch conv2 A-frags (wave's 2 M-tiles x 8 K-tiles) ----
  const uint4* W2 = (const uint4*)w2q;             // idx = ch*32 + c1
  const int mt2 = (wv & 1) * 2;                    // conv2 M-tile pair base
  const int ntb2 = (wv >> 1) * 4;                  // conv2 N-tile base
  uint4 wk2[2][8];
#pragma unroll
  for (int mi = 0; mi < 2; ++mi)
#pragma unroll
    for (int kt = 0; kt < 8; ++kt)
      wk2[mi][kt] = W2[((mt2+mi)*16 + col)*32 + kt*4 + quad];

  // stage base tile + biases + zero h2 tail (dwords 64..71 of each row)
  {
    const int pb = 8*s3 - 14;
    for (int idx = tid; idx < 520; idx += 256) {
      int p = pb + idx;
      sb[idx] = (idx < 517 && p >= 0 && p < LSIG) ? x[p] : 0.0f;
    }
    if (tid < 64) sbias2[tid] = c2b[tid];
    else if (tid < 192) sbias3[tid-64] = c3b[tid-64];
    for (int q = tid; q < 512; q += 256)
      sh2[(q >> 3)*S2DW2 + 64 + (q & 7)] = 0u;
  }
  __syncthreads();

  // conv1: 32 ch, positions 0..256 -> bf16 pairs (dwords 0..131; 129..131 zero)
  {
    const int c1 = tid & 31, g = tid >> 5;
    const float u0=c1w[c1*5+0], u1=c1w[c1*5+1], u2=c1w[c1*5+2], u3=c1w[c1*5+3], u4=c1w[c1*5+4];
    const float bb = c1b[c1];
    const int a1 = 4*s3 - 6;
    for (int j = g; j < 132; j += 8) {
      float r0 = 0.f, r1 = 0.f;
      if (j <= 128) {
        float v0=sb[4*j+0],v1=sb[4*j+1],v2=sb[4*j+2],v3=sb[4*j+3],v4=sb[4*j+4],v5=sb[4*j+5],v6=sb[4*j+6];
        int o0 = a1 + 2*j;
        if (o0 >= 0 && o0 < O1C)
          r0 = lrelu(bb + u0*v0+u1*v1+u2*v2+u3*v3+u4*v4);
        if (2*j+1 <= 256 && o0+1 >= 0 && o0+1 < O1C)
          r1 = lrelu(bb + u0*v2+u1*v3+u2*v4+u3*v5+u4*v6);
      }
      sh1[c1*S1DW2 + j] = pack_bf2(r0, r1);
    }
  }
  __syncthreads();

  // conv2 MFMA: 2 mt x 4 nt, K-tiles 0..7; B-frag shared across the 2 mt
  f32x4v acc2[2][4];
#pragma unroll
  for (int mi = 0; mi < 2; ++mi)
#pragma unroll
    for (int nt = 0; nt < 4; ++nt) acc2[mi][nt] = (f32x4v){0,0,0,0};
#pragma unroll
  for (int kt = 0; kt < 8; ++kt) {
    const int c1 = kt*4 + quad;
#pragma unroll
    for (int nt = 0; nt < 4; ++nt) {
      const int n = (ntb2 + nt)*16 + col;
      const int base = c1*S1DW2 + n;
      BFrag bf;
      bf.u[0] = sh1[base+0]; bf.u[1] = sh1[base+1];
      bf.u[2] = sh1[base+2]; bf.u[3] = sh1[base+3];
      AFrag a0, a1; a0.q = wk2[0][kt]; a1.q = wk2[1][kt];
      acc2[0][nt] = __builtin_amdgcn_mfma_f32_16x16x32_bf16(a0.s, bf.s, acc2[0][nt], 0, 0, 0);
      acc2[1][nt] = __builtin_amdgcn_mfma_f32_16x16x32_bf16(a1.s, bf.s, acc2[1][nt], 0, 0, 0);
    }
  }

  // ---- prefetch conv3 A-frags (overlaps conv2 epilogue + barrier) ----
  const uint4* W3 = (const uint4*)w3q;             // idx = ch*64 + c2
  uint4 wk3[2][16];
#pragma unroll
  for (int mi = 0; mi < 2; ++mi)
#pragma unroll
    for (int kt = 0; kt < 16; ++kt)
      wk3[mi][kt] = W3[((2*wv+mi)*16 + col)*64 + kt*4 + quad];

  // conv2 epilogue: bias + lrelu + bounds -> h2 bf16
  {
    const int a2 = 2*s3 - 2;
    unsigned short* sh2s = (unsigned short*)sh2;
#pragma unroll
    for (int nt = 0; nt < 4; ++nt) {
      const int p = (ntb2 + nt)*16 + col;
      const int o2 = a2 + p;
      const bool ok = (p < 127) && (o2 >= 0) && (o2 < O2C);
#pragma unroll
      for (int mi = 0; mi < 2; ++mi)
#pragma unroll
        for (int r = 0; r < 4; ++r) {
          const int ch = (mt2+mi)*16 + quad*4 + r;
          float v = ok ? lrelu(acc2[mi][nt][r] + sbias2[ch]) : 0.0f;
          sh2s[ch*(2*S2DW2) + p] = (unsigned short)rbf(v);
        }
    }
  }
  __syncthreads();

  // conv3 MFMA: 2 mt x 4 nt, K-tiles 0..15
  {
    const int slot = (blk & 255) * 128;
    f32x4v acc3[2][4];
#pragma unroll
    for (int mi = 0; mi < 2; ++mi)
#pragma unroll
      for (int nt = 0; nt < 4; ++nt) acc3[mi][nt] = (f32x4v){0,0,0,0};
#pragma unroll
    for (int kt = 0; kt < 16; ++kt) {
      const int c2 = kt*4 + quad;
#pragma unroll
      for (int nt = 0; nt < 4; ++nt) {
        const int n = nt*16 + col;
        const int base = c2*S2DW2 + n;
        BFrag bf;
        bf.u[0] = sh2[base+0]; bf.u[1] = sh2[base+1];
        bf.u[2] = sh2[base+2]; bf.u[3] = sh2[base+3];
        AFrag a0, a1; a0.q = wk3[0][kt]; a1.q = wk3[1][kt];
        acc3[0][nt] = __builtin_amdgcn_mfma_f32_16x16x32_bf16(a0.s, bf.s, acc3[0][nt], 0, 0, 0);
        acc3[1][nt] = __builtin_amdgcn_mfma_f32_16x16x32_bf16(a1.s, bf.s, acc3[1][nt], 0, 0, 0);
      }
    }
    // epilogue: bias+lrelu, mask, sum over nt + col lanes, atomic to feat
#pragma unroll
    for (int mi = 0; mi < 2; ++mi)
#pragma unroll
      for (int r = 0; r < 4; ++r) {
        const int ch = (2*wv+mi)*16 + quad*4 + r;
        const float bb = sbias3[ch];
        float v = 0.0f;
#pragma unroll
        for (int nt = 0; nt < 4; ++nt) {
          const int n = nt*16 + col;
          const bool ok = (n < TO3) && (s3 + n < O3C);
          if (ok) v += lrelu(acc3[mi][nt][r] + bb);
        }
        v += __shfl_xor(v, 1);
        v += __shfl_xor(v, 2);
        v += __shfl_xor(v, 4);
        v += __shfl_xor(v, 8);
        if (col == 0) atomicAdd(&feat[slot + ch], v);
      }
  }
}

// final mean + 2-layer MLP -> one f32 scalar
__global__ __launch_bounds__(256) void kfinal(const float* __restrict__ feat,
    const float* __restrict__ mw1, const float* __restrict__ mb1,
    const float* __restrict__ mw2, const float* __restrict__ mb2,
    float* __restrict__ out) {
  __shared__ float sfeat[128];
  __shared__ float red[256];
  const int tid = threadIdx.x;
  if (tid < 128) {
    float s = 0.0f;
    for (int sl = 0; sl < 256; ++sl) s += feat[sl*128 + tid];
    sfeat[tid] = s / 262145.0f;
  }
  __syncthreads();
  float y = mb1[tid];
  for (int i = 0; i < 128; ++i) y += sfeat[i] * mw1[i*256 + tid];
  y = y > 0.0f ? y : 0.2f*y;
  red[tid] = y * mw2[tid];
  __syncthreads();
  for (int off = 128; off > 0; off >>= 1) {
    if (tid < off) red[tid] += red[tid+off];
    __syncthreads();
  }
  if (tid == 0) out[0] = red[0] + mb2[0];
}

extern "C" void kernel_launch(void* const* d_in, const int* in_sizes, int n_in,
                              void* d_out, int out_size, void* d_ws, size_t ws_size,
                              hipStream_t stream) {
  (void)in_sizes; (void)n_in; (void)out_size; (void)ws_size;
  const float* z   = (const float*)d_in[0];
  const float* bw  = (const float*)d_in[2];
  const float* fw  = (const float*)d_in[3];
  const float* hp  = (const float*)d_in[4];
  const float* tw1 = (const float*)d_in[5];
  const float* tb1 = (const float*)d_in[6];
  const float* tw2 = (const float*)d_in[7];
  const float* tb2 = (const float*)d_in[8];
  const float* tw3 = (const float*)d_in[9];
  const float* tb3 = (const float*)d_in[10];
  const float* c1w = (const float*)d_in[11];
  const float* c1b = (const float*)d_in[12];
  const float* c2w = (const float*)d_in[13];
  const float* c2b = (const float*)d_in[14];
  const float* c3w = (const float*)d_in[15];
  const float* c3b = (const float*)d_in[16];
  const float* mw1 = (const float*)d_in[17];
  const float* mb1 = (const float*)d_in[18];
  const float* mw2 = (const float*)d_in[19];
  const float* mb2 = (const float*)d_in[20];

  char* wsb = (char*)d_ws;
  float2* A    = (float2*)(wsb + A_OFF);
  float2* B    = (float2*)(wsb + B_OFF);
  float2* C    = (float2*)(wsb + C_OFF);
  float*  D    = (float*)(wsb + D_OFF);
  float*  PM   = (float*)(wsb + PM_OFF);
  float*  FEAT = (float*)(wsb + FEAT_OFF);
  unsigned short* W2Q = (unsigned short*)(wsb + W2Q_OFF);
  unsigned short* W3Q = (unsigned short*)(wsb + W3Q_OFF);

  // static harmonic-window table
  SmultTab tab;
  {
    const double spec[8] = {7.83, 528.0, 396.0, 2.5, 14.1, 432.0, 6.0, 30.0};
    int n = 0, maxe = 0;
    for (int kk = 0; kk < 8; ++kk)
      for (int m = 1; m <= 5; ++m) {
        double hf = spec[kk] * (double)m;
        if (hf >= 11025.0) continue;
        int hidx = (int)std::floor(hf * (4194304.0/22050.0) + 0.5);
        tab.hidx[n]  = hidx;
        tab.inv12[n] = (float)(1.0/std::pow((double)m, 1.2));
        tab.fk[n]    = kk;
        if (hidx + 15 > maxe) maxe = hidx + 15;
        ++n;
      }
    tab.maxe = maxe;  // n == 40
  }

  (void)hipMemsetAsync(wsb + PM_OFF, 0, 4 + 131072, stream);   // PM + FEAT accumulators
  kprog<<<2048,256,0,stream>>>(tw1,tb1,tw2,tb2,tw3,tb3,hp,PM);

  // forward cfft: radix 64,64,64,8 (kpack fused into the first pass)
  kfft64<true,true ><<<1024,256,0,stream>>>(A, A, 1,     z);
  kfft64<true,false><<<1024,256,0,stream>>>(A, B, 64,    z);
  kfft64<true,false><<<1024,256,0,stream>>>(B, A, 4096,  z);
  kfft8 <true>      <<<1024,256,0,stream>>>(A, B, 262144);

  ksplit<<<8193,256,0,stream>>>(B, C, D, bw, fw, PM, tab);
  ksmooth<<<8192,256,0,stream>>>(C, D, A);
  // D region is now free: pack MFMA weights into it
  kwq<<<256,256,0,stream>>>(c2w, c3w, W2Q, W3Q);

  // inverse cfft: radix 64,64,64,8
  kfft64<false,false><<<1024,256,0,stream>>>(A, B, 1,     z);
  kfft64<false,false><<<1024,256,0,stream>>>(B, A, 64,    z);
  kfft64<false,false><<<1024,256,0,stream>>>(A, B, 4096,  z);
  kfft8 <false>      <<<1024,256,0,stream>>>(B, A, 262144);

  kconv<<<NB3,256,0,stream>>>((const float*)A, W2Q, W3Q, c1w, c1b, c2b, c3b, FEAT);
  kfinal<<<1,256,0,stream>>>(FEAT, mw1, mb1, mw2, mb2, (float*)d_out);
}

// Round 12
// 389.592 us; speedup vs baseline: 1.0951x; 1.0251x over previous
//
#include <hip/hip_runtime.h>
#include <cmath>

// Problem constants
#define LSIG  2097153      // signal / rfft length (= NFFT/2+1)
#define MH    2097152      // NFFT/2 (complex FFT size for packed real trick)
#define NFFTC 4194304      // 2^22
#define NT    262144       // MH/8 = threads per radix-8 FFT pass
#define NT64  32768        // MH/64 = butterflies per radix-64 pass
#define O1C   1048577
#define O2C   524289
#define O3C   262145

// conv tiling: 62 o3 positions per block
#define TO3   62
#define NB3   4229         // ceil(O3C/TO3)
#define S1DW2 136          // h1 dword stride (== 8 mod 32)
#define S2DW2 72           // h2 dword stride (== 8 mod 32)

// Workspace byte offsets
#define A_OFF    0
#define B_OFF    16777216
#define PM_OFF   58720268
#define FEAT_OFF 58720272
// packed bf16 weights (written by kspectral's tail blocks), 16B aligned
#define W2Q_OFF  50331664  // 64*32*8 bf16 = 32768 B
#define W3Q_OFF  50364432  // 128*64*8 bf16 = 131072 B

struct SmultTab { int hidx[40]; float inv12[40]; int fk[40]; int maxe; };

typedef short short8 __attribute__((ext_vector_type(8)));
typedef float f32x4v __attribute__((ext_vector_type(4)));

union AFrag { uint4 q; short8 s; };
union BFrag { unsigned int u[4]; short8 s; };

__device__ __forceinline__ float lrelu(float a){ return a > 0.0f ? a : 0.2f*a; }

// HW transcendentals: v_sin_f32 / v_cos_f32 take input in REVOLUTIONS.
__device__ __forceinline__ float hsin(float rev){ return __builtin_amdgcn_sinf(rev); }
__device__ __forceinline__ float hcos(float rev){ return __builtin_amdgcn_cosf(rev); }

// bf16 pack helpers (round-nearest-even)
__device__ __forceinline__ unsigned int rbf(float f) {
  unsigned int u = __float_as_uint(f);
  u += 0x7fffu + ((u >> 16) & 1u);
  return u >> 16;
}
__device__ __forceinline__ unsigned int pack_bf2(float a, float b) {
  return rbf(a) | (rbf(b) << 16);
}

__device__ __forceinline__ float2 cadd(float2 a, float2 b){ return make_float2(a.x+b.x, a.y+b.y); }
__device__ __forceinline__ float2 csub(float2 a, float2 b){ return make_float2(a.x-b.x, a.y-b.y); }
__device__ __forceinline__ float2 cmul(float2 a, float2 b){ return make_float2(a.x*b.x - a.y*b.y, a.x*b.y + a.y*b.x); }

// multiply by -i (FWD) or +i (INV)
template<bool FWD> __device__ __forceinline__ float2 jrot(float2 z){
  return FWD ? make_float2(z.y, -z.x) : make_float2(-z.y, z.x);
}

// natural-order radix-8 DFT butterfly
template<bool FWD> __device__ __forceinline__ void dft8(float2 v[8]) {
  const float cq = 0.70710678118654752440f;
  const float S  = FWD ? -1.0f : 1.0f;
  float2 e0 = cadd(v[0], v[4]), e1 = csub(v[0], v[4]);
  float2 e2 = cadd(v[2], v[6]), e3 = csub(v[2], v[6]);
  float2 E0 = cadd(e0, e2), E2 = csub(e0, e2);
  float2 jt = jrot<FWD>(e3);
  float2 E1 = cadd(e1, jt), E3 = csub(e1, jt);
  float2 o0 = cadd(v[1], v[5]), o1 = csub(v[1], v[5]);
  float2 o2 = cadd(v[3], v[7]), o3 = csub(v[3], v[7]);
  float2 O0 = cadd(o0, o2), O2 = csub(o0, o2);
  float2 jo = jrot<FWD>(o3);
  float2 O1 = cadd(o1, jo), O3 = csub(o1, jo);
  float2 T1 = make_float2(cq, S*cq), T3 = make_float2(-cq, S*cq);
  float2 w1 = cmul(T1, O1);
  float2 w2 = jrot<FWD>(O2);
  float2 w3 = cmul(T3, O3);
  v[0] = cadd(E0, O0); v[4] = csub(E0, O0);
  v[1] = cadd(E1, w1); v[5] = csub(E1, w1);
  v[2] = cadd(E2, w2); v[6] = csub(E2, w2);
  v[3] = cadd(E3, w3); v[7] = csub(E3, w3);
}

// One Stockham radix-8 pass over MH complex points (used for the Ns=64^3 tail pass).
template<bool FWD>
__global__ __launch_bounds__(256) void kfft8(const float2* __restrict__ src,
                                             float2* __restrict__ dst, int Ns) {
  int j = blockIdx.x*256 + threadIdx.x;          // j in [0, MH/8)
  int m = j & (Ns - 1);
  const float ssg = FWD ? -1.0f : 1.0f;
  float frac = (float)m / (float)(Ns * 8);       // revolutions, exact
  float2 v[8];
  v[0] = src[j];
#pragma unroll
  for (int r = 1; r < 8; ++r) {
    float2 a = src[j + r*NT];
    float rev = frac * (float)r;
    float sn = ssg * hsin(rev), cs = hcos(rev);
    v[r] = make_float2(a.x*cs - a.y*sn, a.x*sn + a.y*cs);
  }
  dft8<FWD>(v);
  int base = ((j - m) << 3) + m;                 // (j/Ns)*Ns*8 + j%Ns
#pragma unroll
  for (int r = 0; r < 8; ++r) dst[base + r*Ns] = v[r];
}

// Stockham radix-64 pass: 32 butterflies/block, 8 lanes per butterfly.
// FIRST=true: reads padded real signal directly (fused kpack): A[n]=z[2n]+i z[2n+1]
template<bool FWD, bool FIRST>
__global__ __launch_bounds__(256) void kfft64(const float2* __restrict__ src,
                                              float2* __restrict__ dst, int Ns,
                                              const float* __restrict__ zin) {
  __shared__ float2 ex[32*65];                   // 65 f2/butterfly (pad vs 64)
  const int t = threadIdx.x;
  const int b = t >> 3, i = t & 7;               // butterfly-in-block, r0 index
  const int j = blockIdx.x*32 + b;               // butterfly index < NT64
  const int m = j & (Ns - 1);
  const float ssg = FWD ? -1.0f : 1.0f;
  const float invden = 1.0f / (float)(64 * Ns);  // exact (power-of-two)
  float2 v[8];
#pragma unroll
  for (int r1 = 0; r1 < 8; ++r1) {
    const int r = 8*r1 + i;
    const int n = j + r * NT64;
    float2 a;
    if (FIRST) {
      if (n < 1048576)       a = ((const float2*)zin)[n];
      else if (n == 1048576) a = make_float2(zin[2097152], 0.0f);
      else                   a = make_float2(0.0f, 0.0f);
    } else {
      a = src[n];
    }
    float rev = (float)(m * r) * invden;         // revolutions, exact (m*r < 2^24)
    float sn = ssg * hsin(rev), cs = hcos(rev);
    v[r1] = make_float2(a.x*cs - a.y*sn, a.x*sn + a.y*cs);
  }
  dft8<FWD>(v);                                   // over r1 -> v[k1]
#pragma unroll
  for (int k1 = 0; k1 < 8; ++k1) {                // intra twiddle W64^{i k1}
    float rev = (float)(i*k1) * 0.015625f;        // revolutions, exact
    float sn = ssg * hsin(rev), cs = hcos(rev);
    ex[b*65 + k1*8 + i] = make_float2(v[k1].x*cs - v[k1].y*sn, v[k1].x*sn + v[k1].y*cs);
  }
  __syncthreads();
  float2 u[8];
#pragma unroll
  for (int r0 = 0; r0 < 8; ++r0) u[r0] = ex[b*65 + i*8 + r0];
  dft8<FWD>(u);                                   // over r0 -> u[k0], k = i + 8 k0
  const int base = (j - m)*64 + m;
#pragma unroll
  for (int k0 = 0; k0 < 8; ++k0) dst[base + (8*k0 + i)*Ns] = u[k0];
}

// prog_mean reduction
__global__ __launch_bounds__(256) void kprog(
    const float* __restrict__ tw1, const float* __restrict__ tb1,
    const float* __restrict__ tw2, const float* __restrict__ tb2,
    const float* __restrict__ tw3, const float* __restrict__ tb3,
    const float* __restrict__ hp, float* __restrict__ pm) {
  __shared__ float sw1[32], sb1[32], sw2[512], sb2[16], sw3[16], shp[8], sb31[1];
  __shared__ float red[256];
  const int tid = threadIdx.x;
  if (tid < 32) { sw1[tid] = tw1[tid]; sb1[tid] = tb1[tid]; }
  for (int q = tid; q < 512; q += 256) sw2[q] = tw2[q];
  if (tid < 16) { sb2[tid] = tb2[tid]; sw3[tid] = tw3[tid*8+1]; }
  if (tid < 8) { float s = 0.f; for (int j = 0; j < 4; ++j) s += hp[tid*4+j]; shp[tid] = s; }
  if (tid == 0) sb31[0] = tb3[1];
  __syncthreads();
  const int gid = blockIdx.x*256 + tid;          // grid = 2048 blocks -> gid < 524288
  const float Lf = 2097153.0f;
  float tnv[4], sv[4];
  int ci[4];
  float acc[4][16];
#pragma unroll
  for (int e = 0; e < 4; ++e) {
    float ti = (float)(gid + e*524288);
    float tn = ti / Lf;
    tnv[e] = tn;
    sv[e] = hsin(tn);                            // sin(2*pi*ti/L)
    ci[e] = ((int)floorf(tn * 8.0f)) & 7;
#pragma unroll
    for (int kk = 0; kk < 16; ++kk) acc[e][kk] = sb2[kk];
  }
  for (int j = 0; j < 32; ++j) {
    float a = sw1[j], b = sb1[j];
    float hj[4];
#pragma unroll
    for (int e = 0; e < 4; ++e) hj[e] = fmaxf(a*tnv[e] + b, 0.0f);
#pragma unroll
    for (int kk = 0; kk < 16; ++kk) {
      float w = sw2[j*16 + kk];
#pragma unroll
      for (int e = 0; e < 4; ++e) acc[e][kk] += hj[e]*w;
    }
  }
  float lsum = 0.0f;
#pragma unroll
  for (int e = 0; e < 4; ++e) {
    float mp1 = sb31[0];
#pragma unroll
    for (int kk = 0; kk < 16; ++kk) mp1 += fmaxf(acc[e][kk], 0.0f)*sw3[kk];
    lsum += shp[ci[e]] * (1.0f + mp1*sv[e]);
  }
  if (gid == 0) {                                 // tail element i = L-1 = 2097152
    float ti = 2097152.0f;
    float tn = ti / Lf;
    float a1[16];
    for (int kk = 0; kk < 16; ++kk) a1[kk] = sb2[kk];
    for (int j = 0; j < 32; ++j) {
      float h = fmaxf(sw1[j]*tn + sb1[j], 0.0f);
      for (int kk = 0; kk < 16; ++kk) a1[kk] += h*sw2[j*16+kk];
    }
    float mp1 = sb31[0];
    for (int kk = 0; kk < 16; ++kk) mp1 += fmaxf(a1[kk], 0.0f)*sw3[kk];
    float svx = hsin(tn);
    int cix = ((int)floorf(tn * 8.0f)) & 7;
    lsum += shp[cix] * (1.0f + mp1*svx);
  }
  red[tid] = lsum;
  __syncthreads();
  for (int off = 128; off > 0; off >>= 1) {
    if (tid < off) red[tid] += red[tid+off];
    __syncthreads();
  }
  if (tid == 0) atomicAdd(pm, red[0]);
}

// ---- fused spectral stage helpers ----
__device__ __forceinline__ float2 xsplit(float2 zk, float2 zm, float rev) {
  // X(k) = 0.5*(Zk + conj(Zm)) - 0.5i * e^{-2pi i rev} * (Zk - conj(Zm))
  float2 s  = make_float2(zk.x + zm.x, zk.y - zm.y);
  float2 dd = make_float2(zk.x - zm.x, zk.y + zm.y);
  float sn = -hsin(rev), cs = hcos(rev);
  float2 t1 = make_float2(cs*dd.x - sn*dd.y, cs*dd.y + sn*dd.x);
  return make_float2(0.5f*(s.x + t1.y), 0.5f*(s.y - t1.x));
}
__device__ __forceinline__ float2 scale_xc(float2 c, float mg, float ms) {
  if (mg > 0.0f) { float sc = ms/mg; return make_float2(c.x*sc, c.y*sc); }
  return make_float2(ms, 0.0f);
}
__device__ __forceinline__ float2 invpack(int n, float2 a, float2 b) {
  // a = Xc(n), b = Xc(MH-n); returns A[n] = (Xe + i Xo)/MH
  float2 s  = make_float2(a.x + b.x, a.y - b.y);
  float2 dd = make_float2(a.x - b.x, a.y + b.y);
  float rev = (float)n * (1.0f / (float)NFFTC);
  float sn = hsin(rev), cs = hcos(rev);
  float2 xo = make_float2(0.5f*(cs*dd.x - sn*dd.y), 0.5f*(cs*dd.y + sn*dd.x));
  const float sc = 1.0f / (float)MH;
  return make_float2((0.5f*s.x - xo.y)*sc, (0.5f*s.y + xo.x)*sc);
}

// Fused: rfft split + band/harmonic multipliers + magnitude smoothing +
// inverse-rfft pack, for the pair (k, MH-k) per thread. Blocks >= 4096 do
// the conv-weight bf16 packing (former kwq).
__global__ __launch_bounds__(256) void kspectral(const float2* __restrict__ Z,
    float2* __restrict__ A, const float* __restrict__ bwp,
    const float* __restrict__ fwp, const float* __restrict__ pm_in, SmultTab tab,
    const float* __restrict__ c2w, const float* __restrict__ c3w,
    unsigned short* __restrict__ w2q, unsigned short* __restrict__ w3q) {
  const int bb = blockIdx.x;
  const int t = threadIdx.x;
  if (bb >= 4096) {                              // folded weight packing
    int i = (bb - 4096)*256 + t;
    if (i < 16384) {                             // 64 ch * 32 c1 * 8 taps
      int tt = i & 7, c1 = (i >> 3) & 31, ch = i >> 8;
      float v = (tt < 5) ? c2w[ch*160 + c1*5 + tt] : 0.0f;
      w2q[i] = (unsigned short)rbf(v);
    }
    if (i < 65536) {                             // 128 ch * 64 c2 * 8 taps
      int tt = i & 7, c2 = (i >> 3) & 63, ch = i >> 9;
      float v = (tt < 5) ? c3w[ch*320 + c2*5 + tt] : 0.0f;
      w3q[i] = (unsigned short)rbf(v);
    }
    return;
  }
  __shared__ float2 Xlo[258], Xhi[258];
  __shared__ float  Mlo[258], Mhi[258];
  const int k0 = bb * 256;
  const float pm1 = 1.0f + pm_in[0] * (1.0f/8388612.0f);   // 1 + sum/(L*4)
  for (int w = t; w < 258; w += 256) {
    int k = k0 - 1 + w;                          // in [-1, 1048576]
    float2 zk = Z[k & (MH-1)];
    float2 zm = Z[(MH - k) & (MH-1)];
    // lo: X(k) with multipliers
    {
      float2 X = xsplit(zk, zm, (float)k * (1.0f/(float)NFFTC));
      float mv = 1.0f;
      if (k <= 38050) {                          // bands only reach 200 Hz
        const float blo[6] = {1.0f,4.0f,8.0f,13.0f,30.0f,100.0f};
        const float bhi[6] = {4.0f,8.0f,13.0f,30.0f,100.0f,200.0f};
        const float bcn[6] = {2.5f,6.0f,10.5f,21.5f,65.0f,150.0f};
        const float bhw[6] = {0.75f,1.0f,1.25f,4.25f,17.5f,25.0f};
        float f = (float)((double)k * (22050.0/4194304.0));
#pragma unroll
        for (int b = 0; b < 6; ++b) {
          if (f >= blo[b] && f <= bhi[b]) {
            float q = (f - bcn[b]) / bhw[b];
            float mask = expf(-0.5f*q*q);
            double frd = (double)k * ((double)bcn[b] / 22050.0);
            frd -= floor(frd);
            float tm = hsin((float)frd);
            mv *= (1.0f + mask * bwp[b] * (1.0f + 0.2f*tm));
          }
        }
      }
      if (k <= tab.maxe) {
        for (int ww = 0; ww < 40; ++ww) {
          int dlt = k - tab.hidx[ww];
          if (dlt >= -15 && dlt <= 15) {
            float x = (float)dlt * 0.2f;
            float win = expf(-0.5f*x*x);
            float enh = fwp[tab.fk[ww]] * win * tab.inv12[ww] * pm1;
            mv *= (1.0f + enh);
          }
        }
      }
      X.x *= mv; X.y *= mv;
      Xlo[w] = X; Mlo[w] = sqrtf(X.x*X.x + X.y*X.y);
    }
    // hi: X(MH-k) -- roles of zk/zm swap; never touched by multipliers
    {
      float2 X = xsplit(zm, zk, (float)(MH - k) * (1.0f/(float)NFFTC));
      Xhi[w] = X; Mhi[w] = sqrtf(X.x*X.x + X.y*X.y);
    }
  }
  __syncthreads();
  const int k = k0 + t, w = t + 1;
  // lo smoothing (k==MH impossible here; k==0 special)
  float msl = (k == 0) ? Mlo[w] : 0.7f*Mlo[w] + 0.15f*(Mlo[w-1] + Mlo[w+1]);
  float2 xl = scale_xc(Xlo[w], Mlo[w], msl);
  // hi smoothing: k' = MH-k; M(k'-1)=Mhi[w+1], M(k'+1)=Mhi[w-1]; k'==MH when k==0
  float msh = (k == 0) ? Mhi[w] : 0.7f*Mhi[w] + 0.15f*(Mhi[w+1] + Mhi[w-1]);
  float2 xh = scale_xc(Xhi[w], Mhi[w], msh);
  A[k] = invpack(k, xl, xh);
  if (k >= 1) A[MH - k] = invpack(MH - k, xh, xl);
  if (bb == 4095 && t == 255) {                  // self-mirror bin n = MH/2
    float2 Xm = Xlo[257]; float Mm = Mlo[257];   // X(1048576)
    float ms = 0.7f*Mm + 0.15f*(Mlo[256] + Mhi[256]); // M(1048575), M(1048577)
    float2 xm = scale_xc(Xm, Mm, ms);
    A[1048576] = invpack(1048576, xm, xm);
  }
}

// Fused conv1 (VALU) + conv2/conv3 (MFMA implicit GEMM, register-stationary weights).
__global__ __launch_bounds__(256, 2) void kconv(const float* __restrict__ x,
    const unsigned short* __restrict__ w2q, const unsigned short* __restrict__ w3q,
    const float* __restrict__ c1w, const float* __restrict__ c1b,
    const float* __restrict__ c2b, const float* __restrict__ c3b,
    float* __restrict__ feat) {
  __shared__ float sb[520];                  // base tile (517 used)
  __shared__ unsigned int sh1[32*S1DW2];     // h1 bf16 pairs
  __shared__ unsigned int sh2[64*S2DW2];     // h2 bf16 pairs
  __shared__ float sbias2[64], sbias3[128];
  const int tid  = threadIdx.x;
  const int blk  = blockIdx.x;
  const int s3   = blk * TO3;
  const int lane = tid & 63;
  const int wv   = tid >> 6;
  const int col  = lane & 15;
  const int quad = lane >> 4;

  // ---- prefetch conv2 A-frags (wave's 2 M-tiles x 8 K-tiles) ----
  const uint4* W2 = (const uint4*)w2q;             // idx = ch*32 + c1
  const int mt2 = (wv & 1) * 2;                    // conv2 M-tile pair base
  const int ntb2 = (wv >> 1) * 4;                  // conv2 N-tile base
  uint4 wk2[2][8];
#pragma unroll
  for (int mi = 0; mi < 2; ++mi)
#pragma unroll
    for (int kt = 0; kt < 8; ++kt)
      wk2[mi][kt] = W2[((mt2+mi)*16 + col)*32 + kt*4 + quad];

  // stage base tile + biases + zero h2 tail (dwords 64..71 of each row)
  {
    const int pb = 8*s3 - 14;
    for (int idx = tid; idx < 520; idx += 256) {
      int p = pb + idx;
      sb[idx] = (idx < 517 && p >= 0 && p < LSIG) ? x[p] : 0.0f;
    }
    if (tid < 64) sbias2[tid] = c2b[tid];
    else if (tid < 192) sbias3[tid-64] = c3b[tid-64];
    for (int q = tid; q < 512; q += 256)
      sh2[(q >> 3)*S2DW2 + 64 + (q & 7)] = 0u;
  }
  __syncthreads();

  // conv1: 32 ch, positions 0..256 -> bf16 pairs (dwords 0..131; 129..131 zero)
  {
    const int c1 = tid & 31, g = tid >> 5;
    const float u0=c1w[c1*5+0], u1=c1w[c1*5+1], u2=c1w[c1*5+2], u3=c1w[c1*5+3], u4=c1w[c1*5+4];
    const float bb = c1b[c1];
    const int a1 = 4*s3 - 6;
    for (int j = g; j < 132; j += 8) {
      float r0 = 0.f, r1 = 0.f;
      if (j <= 128) {
        float v0=sb[4*j+0],v1=sb[4*j+1],v2=sb[4*j+2],v3=sb[4*j+3],v4=sb[4*j+4],v5=sb[4*j+5],v6=sb[4*j+6];
        int o0 = a1 + 2*j;
        if (o0 >= 0 && o0 < O1C)
          r0 = lrelu(bb + u0*v0+u1*v1+u2*v2+u3*v3+u4*v4);
        if (2*j+1 <= 256 && o0+1 >= 0 && o0+1 < O1C)
          r1 = lrelu(bb + u0*v2+u1*v3+u2*v4+u3*v5+u4*v6);
      }
      sh1[c1*S1DW2 + j] = pack_bf2(r0, r1);
    }
  }
  __syncthreads();

  // conv2 MFMA: 2 mt x 4 nt, K-tiles 0..7; B-frag shared across the 2 mt
  f32x4v acc2[2][4];
#pragma unroll
  for (int mi = 0; mi < 2; ++mi)
#pragma unroll
    for (int nt = 0; nt < 4; ++nt) acc2[mi][nt] = (f32x4v){0,0,0,0};
#pragma unroll
  for (int kt = 0; kt < 8; ++kt) {
    const int c1 = kt*4 + quad;
#pragma unroll
    for (int nt = 0; nt < 4; ++nt) {
      const int n = (ntb2 + nt)*16 + col;
      const int base = c1*S1DW2 + n;
      BFrag bf;
      bf.u[0] = sh1[base+0]; bf.u[1] = sh1[base+1];
      bf.u[2] = sh1[base+2]; bf.u[3] = sh1[base+3];
      AFrag a0, a1; a0.q = wk2[0][kt]; a1.q = wk2[1][kt];
      acc2[0][nt] = __builtin_amdgcn_mfma_f32_16x16x32_bf16(a0.s, bf.s, acc2[0][nt], 0, 0, 0);
      acc2[1][nt] = __builtin_amdgcn_mfma_f32_16x16x32_bf16(a1.s, bf.s, acc2[1][nt], 0, 0, 0);
    }
  }

  // ---- prefetch conv3 A-frags (overlaps conv2 epilogue + barrier) ----
  const uint4* W3 = (const uint4*)w3q;             // idx = ch*64 + c2
  uint4 wk3[2][16];
#pragma unroll
  for (int mi = 0; mi < 2; ++mi)
#pragma unroll
    for (int kt = 0; kt < 16; ++kt)
      wk3[mi][kt] = W3[((2*wv+mi)*16 + col)*64 + kt*4 + quad];

  // conv2 epilogue: bias + lrelu + bounds -> h2 bf16
  {
    const int a2 = 2*s3 - 2;
    unsigned short* sh2s = (unsigned short*)sh2;
#pragma unroll
    for (int nt = 0; nt < 4; ++nt) {
      const int p = (ntb2 + nt)*16 + col;
      const int o2 = a2 + p;
      const bool ok = (p < 127) && (o2 >= 0) && (o2 < O2C);
#pragma unroll
      for (int mi = 0; mi < 2; ++mi)
#pragma unroll
        for (int r = 0; r < 4; ++r) {
          const int ch = (mt2+mi)*16 + quad*4 + r;
          float v = ok ? lrelu(acc2[mi][nt][r] + sbias2[ch]) : 0.0f;
          sh2s[ch*(2*S2DW2) + p] = (unsigned short)rbf(v);
        }
    }
  }
  __syncthreads();

  // conv3 MFMA: 2 mt x 4 nt, K-tiles 0..15
  {
    const int slot = (blk & 255) * 128;
    f32x4v acc3[2][4];
#pragma unroll
    for (int mi = 0; mi < 2; ++mi)
#pragma unroll
      for (int nt = 0; nt < 4; ++nt) acc3[mi][nt] = (f32x4v){0,0,0,0};
#pragma unroll
    for (int kt = 0; kt < 16; ++kt) {
      const int c2 = kt*4 + quad;
#pragma unroll
      for (int nt = 0; nt < 4; ++nt) {
        const int n = nt*16 + col;
        const int base = c2*S2DW2 + n;
        BFrag bf;
        bf.u[0] = sh2[base+0]; bf.u[1] = sh2[base+1];
        bf.u[2] = sh2[base+2]; bf.u[3] = sh2[base+3];
        AFrag a0, a1; a0.q = wk3[0][kt]; a1.q = wk3[1][kt];
        acc3[0][nt] = __builtin_amdgcn_mfma_f32_16x16x32_bf16(a0.s, bf.s, acc3[0][nt], 0, 0, 0);
        acc3[1][nt] = __builtin_amdgcn_mfma_f32_16x16x32_bf16(a1.s, bf.s, acc3[1][nt], 0, 0, 0);
      }
    }
    // epilogue: bias+lrelu, mask, sum over nt + col lanes, atomic to feat
#pragma unroll
    for (int mi = 0; mi < 2; ++mi)
#pragma unroll
      for (int r = 0; r < 4; ++r) {
        const int ch = (2*wv+mi)*16 + quad*4 + r;
        const float bb = sbias3[ch];
        float v = 0.0f;
#pragma unroll
        for (int nt = 0; nt < 4; ++nt) {
          const int n = nt*16 + col;
          const bool ok = (n < TO3) && (s3 + n < O3C);
          if (ok) v += lrelu(acc3[mi][nt][r] + bb);
        }
        v += __shfl_xor(v, 1);
        v += __shfl_xor(v, 2);
        v += __shfl_xor(v, 4);
        v += __shfl_xor(v, 8);
        if (col == 0) atomicAdd(&feat[slot + ch], v);
      }
  }
}

// final mean + 2-layer MLP -> one f32 scalar
__global__ __launch_bounds__(256) void kfinal(const float* __restrict__ feat,
    const float* __restrict__ mw1, const float* __restrict__ mb1,
    const float* __restrict__ mw2, const float* __restrict__ mb2,
    float* __restrict__ out) {
  __shared__ float sfeat[128];
  __shared__ float red[256];
  const int tid = threadIdx.x;
  if (tid < 128) {
    float s = 0.0f;
    for (int sl = 0; sl < 256; ++sl) s += feat[sl*128 + tid];
    sfeat[tid] = s / 262145.0f;
  }
  __syncthreads();
  float y = mb1[tid];
  for (int i = 0; i < 128; ++i) y += sfeat[i] * mw1[i*256 + tid];
  y = y > 0.0f ? y : 0.2f*y;
  red[tid] = y * mw2[tid];
  __syncthreads();
  for (int off = 128; off > 0; off >>= 1) {
    if (tid < off) red[tid] += red[tid+off];
    __syncthreads();
  }
  if (tid == 0) out[0] = red[0] + mb2[0];
}

extern "C" void kernel_launch(void* const* d_in, const int* in_sizes, int n_in,
                              void* d_out, int out_size, void* d_ws, size_t ws_size,
                              hipStream_t stream) {
  (void)in_sizes; (void)n_in; (void)out_size; (void)ws_size;
  const float* z   = (const float*)d_in[0];
  const float* bw  = (const float*)d_in[2];
  const float* fw  = (const float*)d_in[3];
  const float* hp  = (const float*)d_in[4];
  const float* tw1 = (const float*)d_in[5];
  const float* tb1 = (const float*)d_in[6];
  const float* tw2 = (const float*)d_in[7];
  const float* tb2 = (const float*)d_in[8];
  const float* tw3 = (const float*)d_in[9];
  const float* tb3 = (const float*)d_in[10];
  const float* c1w = (const float*)d_in[11];
  const float* c1b = (const float*)d_in[12];
  const float* c2w = (const float*)d_in[13];
  const float* c2b = (const float*)d_in[14];
  const float* c3w = (const float*)d_in[15];
  const float* c3b = (const float*)d_in[16];
  const float* mw1 = (const float*)d_in[17];
  const float* mb1 = (const float*)d_in[18];
  const float* mw2 = (const float*)d_in[19];
  const float* mb2 = (const float*)d_in[20];

  char* wsb = (char*)d_ws;
  float2* A    = (float2*)(wsb + A_OFF);
  float2* B    = (float2*)(wsb + B_OFF);
  float*  PM   = (float*)(wsb + PM_OFF);
  float*  FEAT = (float*)(wsb + FEAT_OFF);
  unsigned short* W2Q = (unsigned short*)(wsb + W2Q_OFF);
  unsigned short* W3Q = (unsigned short*)(wsb + W3Q_OFF);

  // static harmonic-window table
  SmultTab tab;
  {
    const double spec[8] = {7.83, 528.0, 396.0, 2.5, 14.1, 432.0, 6.0, 30.0};
    int n = 0, maxe = 0;
    for (int kk = 0; kk < 8; ++kk)
      for (int m = 1; m <= 5; ++m) {
        double hf = spec[kk] * (double)m;
        if (hf >= 11025.0) continue;
        int hidx = (int)std::floor(hf * (4194304.0/22050.0) + 0.5);
        tab.hidx[n]  = hidx;
        tab.inv12[n] = (float)(1.0/std::pow((double)m, 1.2));
        tab.fk[n]    = kk;
        if (hidx + 15 > maxe) maxe = hidx + 15;
        ++n;
      }
    tab.maxe = maxe;  // n == 40
  }

  (void)hipMemsetAsync(wsb + PM_OFF, 0, 4 + 131072, stream);   // PM + FEAT accumulators
  kprog<<<2048,256,0,stream>>>(tw1,tb1,tw2,tb2,tw3,tb3,hp,PM);

  // forward cfft: radix 64,64,64,8 (kpack fused into the first pass)
  kfft64<true,true ><<<1024,256,0,stream>>>(A, A, 1,     z);
  kfft64<true,false><<<1024,256,0,stream>>>(A, B, 64,    z);
  kfft64<true,false><<<1024,256,0,stream>>>(B, A, 4096,  z);
  kfft8 <true>      <<<1024,256,0,stream>>>(A, B, 262144);

  // fused spectral stage (split + mult + smooth + inverse pack) + weight packing
  kspectral<<<4352,256,0,stream>>>(B, A, bw, fw, PM, tab, c2w, c3w, W2Q, W3Q);

  // inverse cfft: radix 64,64,64,8
  kfft64<false,false><<<1024,256,0,stream>>>(A, B, 1,     z);
  kfft64<false,false><<<1024,256,0,stream>>>(B, A, 64,    z);
  kfft64<false,false><<<1024,256,0,stream>>>(A, B, 4096,  z);
  kfft8 <false>      <<<1024,256,0,stream>>>(B, A, 262144);

  kconv<<<NB3,256,0,stream>>>((const float*)A, W2Q, W3Q, c1w, c1b, c2b, c3b, FEAT);
  kfinal<<<1,256,0,stream>>>(FEAT, mw1, mb1, mw2, mb2, (float*)d_out);
}

// Round 13
// 365.878 us; speedup vs baseline: 1.1661x; 1.0648x over previous
//
#include <hip/hip_runtime.h>
#include <cmath>

// Problem constants
#define LSIG  2097153      // signal / rfft length (= NFFT/2+1)
#define MH    2097152      // NFFT/2 (complex FFT size for packed real trick)
#define NFFTC 4194304      // 2^22
#define NT    262144       // MH/8 = threads per radix-8 FFT pass
#define NT64  32768        // MH/64 = butterflies per radix-64 pass
#define O1C   1048577
#define O2C   524289
#define O3C   262145

// conv tiling: 62 o3 positions per block
#define TO3   62
#define NB3   4229         // ceil(O3C/TO3)
#define S1DW2 136          // h1 dword stride (== 8 mod 32)
#define S2DW2 72           // h2 dword stride (== 8 mod 32)

// Workspace byte offsets
#define A_OFF    0
#define B_OFF    16777216
#define PM_OFF   58720268
#define FEAT_OFF 58720272
// packed bf16 weights (written by kspectral's tail blocks), 16B aligned
#define W2Q_OFF  50331664  // 64*32*8 bf16 = 32768 B
#define W3Q_OFF  50364432  // 128*64*8 bf16 = 131072 B

struct SmultTab { int hidx[40]; float inv12[40]; int fk[40]; int maxe; };

typedef short short8 __attribute__((ext_vector_type(8)));
typedef float f32x4v __attribute__((ext_vector_type(4)));

union AFrag { uint4 q; short8 s; };
union BFrag { unsigned int u[4]; short8 s; };

__device__ __forceinline__ float lrelu(float a){ return a > 0.0f ? a : 0.2f*a; }

// HW transcendentals: v_sin_f32 / v_cos_f32 take input in REVOLUTIONS.
__device__ __forceinline__ float hsin(float rev){ return __builtin_amdgcn_sinf(rev); }
__device__ __forceinline__ float hcos(float rev){ return __builtin_amdgcn_cosf(rev); }

// bf16 pack helpers (round-nearest-even)
__device__ __forceinline__ unsigned int rbf(float f) {
  unsigned int u = __float_as_uint(f);
  u += 0x7fffu + ((u >> 16) & 1u);
  return u >> 16;
}
__device__ __forceinline__ unsigned int pack_bf2(float a, float b) {
  return rbf(a) | (rbf(b) << 16);
}

__device__ __forceinline__ float2 cadd(float2 a, float2 b){ return make_float2(a.x+b.x, a.y+b.y); }
__device__ __forceinline__ float2 csub(float2 a, float2 b){ return make_float2(a.x-b.x, a.y-b.y); }
__device__ __forceinline__ float2 cmul(float2 a, float2 b){ return make_float2(a.x*b.x - a.y*b.y, a.x*b.y + a.y*b.x); }

// multiply by -i (FWD) or +i (INV)
template<bool FWD> __device__ __forceinline__ float2 jrot(float2 z){
  return FWD ? make_float2(z.y, -z.x) : make_float2(-z.y, z.x);
}

// natural-order radix-8 DFT butterfly
template<bool FWD> __device__ __forceinline__ void dft8(float2 v[8]) {
  const float cq = 0.70710678118654752440f;
  const float S  = FWD ? -1.0f : 1.0f;
  float2 e0 = cadd(v[0], v[4]), e1 = csub(v[0], v[4]);
  float2 e2 = cadd(v[2], v[6]), e3 = csub(v[2], v[6]);
  float2 E0 = cadd(e0, e2), E2 = csub(e0, e2);
  float2 jt = jrot<FWD>(e3);
  float2 E1 = cadd(e1, jt), E3 = csub(e1, jt);
  float2 o0 = cadd(v[1], v[5]), o1 = csub(v[1], v[5]);
  float2 o2 = cadd(v[3], v[7]), o3 = csub(v[3], v[7]);
  float2 O0 = cadd(o0, o2), O2 = csub(o0, o2);
  float2 jo = jrot<FWD>(o3);
  float2 O1 = cadd(o1, jo), O3 = csub(o1, jo);
  float2 T1 = make_float2(cq, S*cq), T3 = make_float2(-cq, S*cq);
  float2 w1 = cmul(T1, O1);
  float2 w2 = jrot<FWD>(O2);
  float2 w3 = cmul(T3, O3);
  v[0] = cadd(E0, O0); v[4] = csub(E0, O0);
  v[1] = cadd(E1, w1); v[5] = csub(E1, w1);
  v[2] = cadd(E2, w2); v[6] = csub(E2, w2);
  v[3] = cadd(E3, w3); v[7] = csub(E3, w3);
}

// One Stockham radix-8 pass over MH complex points (used for the Ns=64^3 tail pass).
template<bool FWD>
__global__ __launch_bounds__(256) void kfft8(const float2* __restrict__ src,
                                             float2* __restrict__ dst, int Ns) {
  int j = blockIdx.x*256 + threadIdx.x;          // j in [0, MH/8)
  int m = j & (Ns - 1);
  const float ssg = FWD ? -1.0f : 1.0f;
  float frac = (float)m / (float)(Ns * 8);       // revolutions, exact
  float2 v[8];
  v[0] = src[j];
#pragma unroll
  for (int r = 1; r < 8; ++r) {
    float2 a = src[j + r*NT];
    float rev = frac * (float)r;
    float sn = ssg * hsin(rev), cs = hcos(rev);
    v[r] = make_float2(a.x*cs - a.y*sn, a.x*sn + a.y*cs);
  }
  dft8<FWD>(v);
  int base = ((j - m) << 3) + m;                 // (j/Ns)*Ns*8 + j%Ns
#pragma unroll
  for (int r = 0; r < 8; ++r) dst[base + r*Ns] = v[r];
}

// Stockham radix-64 pass: 32 butterflies/block, 8 lanes per butterfly.
// FIRST=true: reads padded real signal directly (fused kpack): A[n]=z[2n]+i z[2n+1]
template<bool FWD, bool FIRST>
__global__ __launch_bounds__(256) void kfft64(const float2* __restrict__ src,
                                              float2* __restrict__ dst, int Ns,
                                              const float* __restrict__ zin) {
  __shared__ float2 ex[32*65];                   // 65 f2/butterfly (pad vs 64)
  const int t = threadIdx.x;
  const int b = t >> 3, i = t & 7;               // butterfly-in-block, r0 index
  const int j = blockIdx.x*32 + b;               // butterfly index < NT64
  const int m = j & (Ns - 1);
  const float ssg = FWD ? -1.0f : 1.0f;
  const float invden = 1.0f / (float)(64 * Ns);  // exact (power-of-two)
  float2 v[8];
#pragma unroll
  for (int r1 = 0; r1 < 8; ++r1) {
    const int r = 8*r1 + i;
    const int n = j + r * NT64;
    float2 a;
    if (FIRST) {
      if (n < 1048576)       a = ((const float2*)zin)[n];
      else if (n == 1048576) a = make_float2(zin[2097152], 0.0f);
      else                   a = make_float2(0.0f, 0.0f);
    } else {
      a = src[n];
    }
    float rev = (float)(m * r) * invden;         // revolutions, exact (m*r < 2^24)
    float sn = ssg * hsin(rev), cs = hcos(rev);
    v[r1] = make_float2(a.x*cs - a.y*sn, a.x*sn + a.y*cs);
  }
  dft8<FWD>(v);                                   // over r1 -> v[k1]
#pragma unroll
  for (int k1 = 0; k1 < 8; ++k1) {                // intra twiddle W64^{i k1}
    float rev = (float)(i*k1) * 0.015625f;        // revolutions, exact
    float sn = ssg * hsin(rev), cs = hcos(rev);
    ex[b*65 + k1*8 + i] = make_float2(v[k1].x*cs - v[k1].y*sn, v[k1].x*sn + v[k1].y*cs);
  }
  __syncthreads();
  float2 u[8];
#pragma unroll
  for (int r0 = 0; r0 < 8; ++r0) u[r0] = ex[b*65 + i*8 + r0];
  dft8<FWD>(u);                                   // over r0 -> u[k0], k = i + 8 k0
  const int base = (j - m)*64 + m;
#pragma unroll
  for (int k0 = 0; k0 < 8; ++k0) dst[base + (8*k0 + i)*Ns] = u[k0];
}

// prog_mean reduction
__global__ __launch_bounds__(256) void kprog(
    const float* __restrict__ tw1, const float* __restrict__ tb1,
    const float* __restrict__ tw2, const float* __restrict__ tb2,
    const float* __restrict__ tw3, const float* __restrict__ tb3,
    const float* __restrict__ hp, float* __restrict__ pm) {
  __shared__ float sw1[32], sb1[32], sw2[512], sb2[16], sw3[16], shp[8], sb31[1];
  __shared__ float red[256];
  const int tid = threadIdx.x;
  if (tid < 32) { sw1[tid] = tw1[tid]; sb1[tid] = tb1[tid]; }
  for (int q = tid; q < 512; q += 256) sw2[q] = tw2[q];
  if (tid < 16) { sb2[tid] = tb2[tid]; sw3[tid] = tw3[tid*8+1]; }
  if (tid < 8) { float s = 0.f; for (int j = 0; j < 4; ++j) s += hp[tid*4+j]; shp[tid] = s; }
  if (tid == 0) sb31[0] = tb3[1];
  __syncthreads();
  const int gid = blockIdx.x*256 + tid;          // grid = 2048 blocks -> gid < 524288
  const float Lf = 2097153.0f;
  float tnv[4], sv[4];
  int ci[4];
  float acc[4][16];
#pragma unroll
  for (int e = 0; e < 4; ++e) {
    float ti = (float)(gid + e*524288);
    float tn = ti / Lf;
    tnv[e] = tn;
    sv[e] = hsin(tn);                            // sin(2*pi*ti/L)
    ci[e] = ((int)floorf(tn * 8.0f)) & 7;
#pragma unroll
    for (int kk = 0; kk < 16; ++kk) acc[e][kk] = sb2[kk];
  }
  for (int j = 0; j < 32; ++j) {
    float a = sw1[j], b = sb1[j];
    float hj[4];
#pragma unroll
    for (int e = 0; e < 4; ++e) hj[e] = fmaxf(a*tnv[e] + b, 0.0f);
#pragma unroll
    for (int kk = 0; kk < 16; ++kk) {
      float w = sw2[j*16 + kk];
#pragma unroll
      for (int e = 0; e < 4; ++e) acc[e][kk] += hj[e]*w;
    }
  }
  float lsum = 0.0f;
#pragma unroll
  for (int e = 0; e < 4; ++e) {
    float mp1 = sb31[0];
#pragma unroll
    for (int kk = 0; kk < 16; ++kk) mp1 += fmaxf(acc[e][kk], 0.0f)*sw3[kk];
    lsum += shp[ci[e]] * (1.0f + mp1*sv[e]);
  }
  if (gid == 0) {                                 // tail element i = L-1 = 2097152
    float ti = 2097152.0f;
    float tn = ti / Lf;
    float a1[16];
    for (int kk = 0; kk < 16; ++kk) a1[kk] = sb2[kk];
    for (int j = 0; j < 32; ++j) {
      float h = fmaxf(sw1[j]*tn + sb1[j], 0.0f);
      for (int kk = 0; kk < 16; ++kk) a1[kk] += h*sw2[j*16+kk];
    }
    float mp1 = sb31[0];
    for (int kk = 0; kk < 16; ++kk) mp1 += fmaxf(a1[kk], 0.0f)*sw3[kk];
    float svx = hsin(tn);
    int cix = ((int)floorf(tn * 8.0f)) & 7;
    lsum += shp[cix] * (1.0f + mp1*svx);
  }
  red[tid] = lsum;
  __syncthreads();
  for (int off = 128; off > 0; off >>= 1) {
    if (tid < off) red[tid] += red[tid+off];
    __syncthreads();
  }
  if (tid == 0) atomicAdd(pm, red[0]);
}

// ---- fused spectral stage helpers ----
__device__ __forceinline__ float2 xsplit(float2 zk, float2 zm, float rev) {
  float2 s  = make_float2(zk.x + zm.x, zk.y - zm.y);
  float2 dd = make_float2(zk.x - zm.x, zk.y + zm.y);
  float sn = -hsin(rev), cs = hcos(rev);
  float2 t1 = make_float2(cs*dd.x - sn*dd.y, cs*dd.y + sn*dd.x);
  return make_float2(0.5f*(s.x + t1.y), 0.5f*(s.y - t1.x));
}
__device__ __forceinline__ float2 scale_xc(float2 c, float mg, float ms) {
  if (mg > 0.0f) { float sc = ms/mg; return make_float2(c.x*sc, c.y*sc); }
  return make_float2(ms, 0.0f);
}
__device__ __forceinline__ float2 invpack(int n, float2 a, float2 b) {
  float2 s  = make_float2(a.x + b.x, a.y - b.y);
  float2 dd = make_float2(a.x - b.x, a.y + b.y);
  float rev = (float)n * (1.0f / (float)NFFTC);
  float sn = hsin(rev), cs = hcos(rev);
  float2 xo = make_float2(0.5f*(cs*dd.x - sn*dd.y), 0.5f*(cs*dd.y + sn*dd.x));
  const float sc = 1.0f / (float)MH;
  return make_float2((0.5f*s.x - xo.y)*sc, (0.5f*s.y + xo.x)*sc);
}

// Fused: rfft split + band/harmonic multipliers + magnitude smoothing +
// inverse-rfft pack, for the pair (k, MH-k) per thread. Blocks >= 4096 do
// the conv-weight bf16 packing.
__global__ __launch_bounds__(256) void kspectral(const float2* __restrict__ Z,
    float2* __restrict__ A, const float* __restrict__ bwp,
    const float* __restrict__ fwp, const float* __restrict__ pm_in, SmultTab tab,
    const float* __restrict__ c2w, const float* __restrict__ c3w,
    unsigned short* __restrict__ w2q, unsigned short* __restrict__ w3q) {
  const int bb = blockIdx.x;
  const int t = threadIdx.x;
  if (bb >= 4096) {                              // folded weight packing
    int i = (bb - 4096)*256 + t;
    if (i < 16384) {
      int tt = i & 7, c1 = (i >> 3) & 31, ch = i >> 8;
      float v = (tt < 5) ? c2w[ch*160 + c1*5 + tt] : 0.0f;
      w2q[i] = (unsigned short)rbf(v);
    }
    if (i < 65536) {
      int tt = i & 7, c2 = (i >> 3) & 63, ch = i >> 9;
      float v = (tt < 5) ? c3w[ch*320 + c2*5 + tt] : 0.0f;
      w3q[i] = (unsigned short)rbf(v);
    }
    return;
  }
  __shared__ float2 Xlo[258], Xhi[258];
  __shared__ float  Mlo[258], Mhi[258];
  const int k0 = bb * 256;
  const float pm1 = 1.0f + pm_in[0] * (1.0f/8388612.0f);   // 1 + sum/(L*4)
  for (int w = t; w < 258; w += 256) {
    int k = k0 - 1 + w;                          // in [-1, 1048576]
    float2 zk = Z[k & (MH-1)];
    float2 zm = Z[(MH - k) & (MH-1)];
    {
      float2 X = xsplit(zk, zm, (float)k * (1.0f/(float)NFFTC));
      float mv = 1.0f;
      if (k <= 38050) {
        const float blo[6] = {1.0f,4.0f,8.0f,13.0f,30.0f,100.0f};
        const float bhi[6] = {4.0f,8.0f,13.0f,30.0f,100.0f,200.0f};
        const float bcn[6] = {2.5f,6.0f,10.5f,21.5f,65.0f,150.0f};
        const float bhw[6] = {0.75f,1.0f,1.25f,4.25f,17.5f,25.0f};
        float f = (float)((double)k * (22050.0/4194304.0));
#pragma unroll
        for (int b = 0; b < 6; ++b) {
          if (f >= blo[b] && f <= bhi[b]) {
            float q = (f - bcn[b]) / bhw[b];
            float mask = expf(-0.5f*q*q);
            double frd = (double)k * ((double)bcn[b] / 22050.0);
            frd -= floor(frd);
            float tm = hsin((float)frd);
            mv *= (1.0f + mask * bwp[b] * (1.0f + 0.2f*tm));
          }
        }
      }
      if (k <= tab.maxe) {
        for (int ww = 0; ww < 40; ++ww) {
          int dlt = k - tab.hidx[ww];
          if (dlt >= -15 && dlt <= 15) {
            float x = (float)dlt * 0.2f;
            float win = expf(-0.5f*x*x);
            float enh = fwp[tab.fk[ww]] * win * tab.inv12[ww] * pm1;
            mv *= (1.0f + enh);
          }
        }
      }
      X.x *= mv; X.y *= mv;
      Xlo[w] = X; Mlo[w] = sqrtf(X.x*X.x + X.y*X.y);
    }
    {
      float2 X = xsplit(zm, zk, (float)(MH - k) * (1.0f/(float)NFFTC));
      Xhi[w] = X; Mhi[w] = sqrtf(X.x*X.x + X.y*X.y);
    }
  }
  __syncthreads();
  const int k = k0 + t, w = t + 1;
  float msl = (k == 0) ? Mlo[w] : 0.7f*Mlo[w] + 0.15f*(Mlo[w-1] + Mlo[w+1]);
  float2 xl = scale_xc(Xlo[w], Mlo[w], msl);
  float msh = (k == 0) ? Mhi[w] : 0.7f*Mhi[w] + 0.15f*(Mhi[w+1] + Mhi[w-1]);
  float2 xh = scale_xc(Xhi[w], Mhi[w], msh);
  A[k] = invpack(k, xl, xh);
  if (k >= 1) A[MH - k] = invpack(MH - k, xh, xl);
  if (bb == 4095 && t == 255) {                  // self-mirror bin n = MH/2
    float2 Xm = Xlo[257]; float Mm = Mlo[257];
    float ms = 0.7f*Mm + 0.15f*(Mlo[256] + Mhi[256]);
    float2 xm = scale_xc(Xm, Mm, ms);
    A[1048576] = invpack(1048576, xm, xm);
  }
}

// Fused conv1 (VALU) + conv2/conv3 (MFMA implicit GEMM).
// Register-footprint-capped variant: conv3 runs as TWO passes of 1 M-tile
// (16 weight-uint4 live instead of 32) so 4 blocks/CU fit the unified
// VGPR/AGPR file. launch_bounds(256,4): budget 128 regs/wave.
__global__ __launch_bounds__(256, 4) void kconv(const float* __restrict__ x,
    const unsigned short* __restrict__ w2q, const unsigned short* __restrict__ w3q,
    const float* __restrict__ c1w, const float* __restrict__ c1b,
    const float* __restrict__ c2b, const float* __restrict__ c3b,
    float* __restrict__ feat) {
  __shared__ float sb[520];                  // base tile (517 used)
  __shared__ unsigned int sh1[32*S1DW2];     // h1 bf16 pairs
  __shared__ unsigned int sh2[64*S2DW2];     // h2 bf16 pairs
  __shared__ float sbias2[64], sbias3[128];
  const int tid  = threadIdx.x;
  const int blk  = blockIdx.x;
  const int s3   = blk * TO3;
  const int lane = tid & 63;
  const int wv   = tid >> 6;
  const int col  = lane & 15;
  const int quad = lane >> 4;

  // ---- prefetch conv2 A-frags (wave's 2 M-tiles x 8 K-tiles) ----
  const uint4* W2 = (const uint4*)w2q;             // idx = ch*32 + c1
  const int mt2 = (wv & 1) * 2;                    // conv2 M-tile pair base
  const int ntb2 = (wv >> 1) * 4;                  // conv2 N-tile base
  uint4 wk2[2][8];
#pragma unroll
  for (int mi = 0; mi < 2; ++mi)
#pragma unroll
    for (int kt = 0; kt < 8; ++kt)
      wk2[mi][kt] = W2[((mt2+mi)*16 + col)*32 + kt*4 + quad];

  // stage base tile + biases + zero h2 tail (dwords 64..71 of each row)
  {
    const int pb = 8*s3 - 14;
    for (int idx = tid; idx < 520; idx += 256) {
      int p = pb + idx;
      sb[idx] = (idx < 517 && p >= 0 && p < LSIG) ? x[p] : 0.0f;
    }
    if (tid < 64) sbias2[tid] = c2b[tid];
    else if (tid < 192) sbias3[tid-64] = c3b[tid-64];
    for (int q = tid; q < 512; q += 256)
      sh2[(q >> 3)*S2DW2 + 64 + (q & 7)] = 0u;
  }
  __syncthreads();

  // conv1: 32 ch, positions 0..256 -> bf16 pairs (dwords 0..131; 129..131 zero)
  {
    const int c1 = tid & 31, g = tid >> 5;
    const float u0=c1w[c1*5+0], u1=c1w[c1*5+1], u2=c1w[c1*5+2], u3=c1w[c1*5+3], u4=c1w[c1*5+4];
    const float bb = c1b[c1];
    const int a1 = 4*s3 - 6;
    for (int j = g; j < 132; j += 8) {
      float r0 = 0.f, r1 = 0.f;
      if (j <= 128) {
        float v0=sb[4*j+0],v1=sb[4*j+1],v2=sb[4*j+2],v3=sb[4*j+3],v4=sb[4*j+4],v5=sb[4*j+5],v6=sb[4*j+6];
        int o0 = a1 + 2*j;
        if (o0 >= 0 && o0 < O1C)
          r0 = lrelu(bb + u0*v0+u1*v1+u2*v2+u3*v3+u4*v4);
        if (2*j+1 <= 256 && o0+1 >= 0 && o0+1 < O1C)
          r1 = lrelu(bb + u0*v2+u1*v3+u2*v4+u3*v5+u4*v6);
      }
      sh1[c1*S1DW2 + j] = pack_bf2(r0, r1);
    }
  }
  __syncthreads();

  // conv2 MFMA: 2 mt x 4 nt, K-tiles 0..7; B-frag shared across the 2 mt
  f32x4v acc2[2][4];
#pragma unroll
  for (int mi = 0; mi < 2; ++mi)
#pragma unroll
    for (int nt = 0; nt < 4; ++nt) acc2[mi][nt] = (f32x4v){0,0,0,0};
#pragma unroll
  for (int kt = 0; kt < 8; ++kt) {
    const int c1 = kt*4 + quad;
#pragma unroll
    for (int nt = 0; nt < 4; ++nt) {
      const int n = (ntb2 + nt)*16 + col;
      const int base = c1*S1DW2 + n;
      BFrag bf;
      bf.u[0] = sh1[base+0]; bf.u[1] = sh1[base+1];
      bf.u[2] = sh1[base+2]; bf.u[3] = sh1[base+3];
      AFrag a0, a1; a0.q = wk2[0][kt]; a1.q = wk2[1][kt];
      acc2[0][nt] = __builtin_amdgcn_mfma_f32_16x16x32_bf16(a0.s, bf.s, acc2[0][nt], 0, 0, 0);
      acc2[1][nt] = __builtin_amdgcn_mfma_f32_16x16x32_bf16(a1.s, bf.s, acc2[1][nt], 0, 0, 0);
    }
  }

  // conv2 epilogue: bias + lrelu + bounds -> h2 bf16
  {
    const int a2 = 2*s3 - 2;
    unsigned short* sh2s = (unsigned short*)sh2;
#pragma unroll
    for (int nt = 0; nt < 4; ++nt) {
      const int p = (ntb2 + nt)*16 + col;
      const int o2 = a2 + p;
      const bool ok = (p < 127) && (o2 >= 0) && (o2 < O2C);
#pragma unroll
      for (int mi = 0; mi < 2; ++mi)
#pragma unroll
        for (int r = 0; r < 4; ++r) {
          const int ch = (mt2+mi)*16 + quad*4 + r;
          float v = ok ? lrelu(acc2[mi][nt][r] + sbias2[ch]) : 0.0f;
          sh2s[ch*(2*S2DW2) + p] = (unsigned short)rbf(v);
        }
    }
  }
  __syncthreads();

  // conv3 MFMA: TWO passes of 1 M-tile x 4 N-tiles x 16 K-tiles.
  // Per pass: 16 weight-uint4 (64 regs) + 16 acc regs -> fits 128-reg budget.
  {
    const uint4* W3 = (const uint4*)w3q;           // idx = ch*64 + c2
    const int slot = (blk & 255) * 128;
#pragma unroll
    for (int pass = 0; pass < 2; ++pass) {
      const int mt = wv + 4*pass;                  // M-tile 0..7
      uint4 wk3[16];
#pragma unroll
      for (int kt = 0; kt < 16; ++kt)
        wk3[kt] = W3[(mt*16 + col)*64 + kt*4 + quad];
      f32x4v acc3[4];
#pragma unroll
      for (int nt = 0; nt < 4; ++nt) acc3[nt] = (f32x4v){0,0,0,0};
#pragma unroll
      for (int kt = 0; kt < 16; ++kt) {
        const int c2 = kt*4 + quad;
#pragma unroll
        for (int nt = 0; nt < 4; ++nt) {
          const int n = nt*16 + col;
          const int base = c2*S2DW2 + n;
          BFrag bf;
          bf.u[0] = sh2[base+0]; bf.u[1] = sh2[base+1];
          bf.u[2] = sh2[base+2]; bf.u[3] = sh2[base+3];
          AFrag a; a.q = wk3[kt];
          acc3[nt] = __builtin_amdgcn_mfma_f32_16x16x32_bf16(a.s, bf.s, acc3[nt], 0, 0, 0);
        }
      }
      // epilogue: bias+lrelu, mask, sum over nt + col lanes, atomic to feat
#pragma unroll
      for (int r = 0; r < 4; ++r) {
        const int ch = mt*16 + quad*4 + r;
        const float bb = sbias3[ch];
        float v = 0.0f;
#pragma unroll
        for (int nt = 0; nt < 4; ++nt) {
          const int n = nt*16 + col;
          const bool ok = (n < TO3) && (s3 + n < O3C);
          if (ok) v += lrelu(acc3[nt][r] + bb);
        }
        v += __shfl_xor(v, 1);
        v += __shfl_xor(v, 2);
        v += __shfl_xor(v, 4);
        v += __shfl_xor(v, 8);
        if (col == 0) atomicAdd(&feat[slot + ch], v);
      }
    }
  }
}

// final mean + 2-layer MLP -> one f32 scalar
__global__ __launch_bounds__(256) void kfinal(const float* __restrict__ feat,
    const float* __restrict__ mw1, const float* __restrict__ mb1,
    const float* __restrict__ mw2, const float* __restrict__ mb2,
    float* __restrict__ out) {
  __shared__ float sfeat[128];
  __shared__ float red[256];
  const int tid = threadIdx.x;
  if (tid < 128) {
    float s = 0.0f;
    for (int sl = 0; sl < 256; ++sl) s += feat[sl*128 + tid];
    sfeat[tid] = s / 262145.0f;
  }
  __syncthreads();
  float y = mb1[tid];
  for (int i = 0; i < 128; ++i) y += sfeat[i] * mw1[i*256 + tid];
  y = y > 0.0f ? y : 0.2f*y;
  red[tid] = y * mw2[tid];
  __syncthreads();
  for (int off = 128; off > 0; off >>= 1) {
    if (tid < off) red[tid] += red[tid+off];
    __syncthreads();
  }
  if (tid == 0) out[0] = red[0] + mb2[0];
}

extern "C" void kernel_launch(void* const* d_in, const int* in_sizes, int n_in,
                              void* d_out, int out_size, void* d_ws, size_t ws_size,
                              hipStream_t stream) {
  (void)in_sizes; (void)n_in; (void)out_size; (void)ws_size;
  const float* z   = (const float*)d_in[0];
  const float* bw  = (const float*)d_in[2];
  const float* fw  = (const float*)d_in[3];
  const float* hp  = (const float*)d_in[4];
  const float* tw1 = (const float*)d_in[5];
  const float* tb1 = (const float*)d_in[6];
  const float* tw2 = (const float*)d_in[7];
  const float* tb2 = (const float*)d_in[8];
  const float* tw3 = (const float*)d_in[9];
  const float* tb3 = (const float*)d_in[10];
  const float* c1w = (const float*)d_in[11];
  const float* c1b = (const float*)d_in[12];
  const float* c2w = (const float*)d_in[13];
  const float* c2b = (const float*)d_in[14];
  const float* c3w = (const float*)d_in[15];
  const float* c3b = (const float*)d_in[16];
  const float* mw1 = (const float*)d_in[17];
  const float* mb1 = (const float*)d_in[18];
  const float* mw2 = (const float*)d_in[19];
  const float* mb2 = (const float*)d_in[20];

  char* wsb = (char*)d_ws;
  float2* A    = (float2*)(wsb + A_OFF);
  float2* B    = (float2*)(wsb + B_OFF);
  float*  PM   = (float*)(wsb + PM_OFF);
  float*  FEAT = (float*)(wsb + FEAT_OFF);
  unsigned short* W2Q = (unsigned short*)(wsb + W2Q_OFF);
  unsigned short* W3Q = (unsigned short*)(wsb + W3Q_OFF);

  // static harmonic-window table
  SmultTab tab;
  {
    const double spec[8] = {7.83, 528.0, 396.0, 2.5, 14.1, 432.0, 6.0, 30.0};
    int n = 0, maxe = 0;
    for (int kk = 0; kk < 8; ++kk)
      for (int m = 1; m <= 5; ++m) {
        double hf = spec[kk] * (double)m;
        if (hf >= 11025.0) continue;
        int hidx = (int)std::floor(hf * (4194304.0/22050.0) + 0.5);
        tab.hidx[n]  = hidx;
        tab.inv12[n] = (float)(1.0/std::pow((double)m, 1.2));
        tab.fk[n]    = kk;
        if (hidx + 15 > maxe) maxe = hidx + 15;
        ++n;
      }
    tab.maxe = maxe;  // n == 40
  }

  (void)hipMemsetAsync(wsb + PM_OFF, 0, 4 + 131072, stream);   // PM + FEAT accumulators
  kprog<<<2048,256,0,stream>>>(tw1,tb1,tw2,tb2,tw3,tb3,hp,PM);

  // forward cfft: radix 64,64,64,8 (kpack fused into the first pass)
  kfft64<true,true ><<<1024,256,0,stream>>>(A, A, 1,     z);
  kfft64<true,false><<<1024,256,0,stream>>>(A, B, 64,    z);
  kfft64<true,false><<<1024,256,0,stream>>>(B, A, 4096,  z);
  kfft8 <true>      <<<1024,256,0,stream>>>(A, B, 262144);

  // fused spectral stage (split + mult + smooth + inverse pack) + weight packing
  kspectral<<<4352,256,0,stream>>>(B, A, bw, fw, PM, tab, c2w, c3w, W2Q, W3Q);

  // inverse cfft: radix 64,64,64,8
  kfft64<false,false><<<1024,256,0,stream>>>(A, B, 1,     z);
  kfft64<false,false><<<1024,256,0,stream>>>(B, A, 64,    z);
  kfft64<false,false><<<1024,256,0,stream>>>(A, B, 4096,  z);
  kfft8 <false>      <<<1024,256,0,stream>>>(B, A, 262144);

  kconv<<<NB3,256,0,stream>>>((const float*)A, W2Q, W3Q, c1w, c1b, c2b, c3b, FEAT);
  kfinal<<<1,256,0,stream>>>(FEAT, mw1, mb1, mw2, mb2, (float*)d_out);
}